// Round 2
// baseline (1585.880 us; speedup 1.0000x reference)
//
#include <hip/hip_runtime.h>
#include <hip/hip_bf16.h>

#define N_NODES 50000
#define D_FEAT  256
#define G_GROUPS 4
#define E_EDGES 800000
#define DG      64
#define M_SEG   (G_GROUPS * N_NODES)        // 200000 segments
#define TOT_E   (G_GROUPS * E_EDGES)        // 3200000 edges
#define M_PAD   50048                       // 391 * 128

// bucket geometry
#define BSEG      128                        // segments per bucket
#define NBUCK     1563                       // ceil(M_SEG / BSEG)
#define NSB       (NBUCK * 8)                // sub-buckets: (bucket, blk&7)
#define CB_BLOCKS 1024
#define CHUNK     (TOT_E / CB_BLOCKS)        // 3125, exact

// scan geometry (single block over NSB)
#define SC_T   1024
#define SC_PER 13                            // 1024*13 = 13312 >= NSB+1

typedef short bf16x8 __attribute__((ext_vector_type(8)));   // 8 bf16 (4 VGPRs)
typedef float f32x4  __attribute__((ext_vector_type(4)));

__device__ __forceinline__ unsigned short f2bf(float f) {
    unsigned int u = __float_as_uint(f);
    u += 0x7FFF + ((u >> 16) & 1);          // RNE
    return (unsigned short)(u >> 16);
}
__device__ __forceinline__ float bf2f(unsigned short h) {
    return __uint_as_float((unsigned int)h << 16);
}

// ---------------------------------------------------------------------------
// x (f32 [N,256]) -> x_bf (bf16). 8 elems / thread.
// ---------------------------------------------------------------------------
__global__ __launch_bounds__(256) void convert_x_kernel(
    const float* __restrict__ x, unsigned short* __restrict__ xb)
{
    const long long base = ((long long)blockIdx.x * 256 + threadIdx.x) * 8;
    if (base >= (long long)N_NODES * D_FEAT) return;
    const float4 v0 = *(const float4*)&x[base];
    const float4 v1 = *(const float4*)&x[base + 4];
    unsigned short r[8];
    r[0] = f2bf(v0.x); r[1] = f2bf(v0.y); r[2] = f2bf(v0.z); r[3] = f2bf(v0.w);
    r[4] = f2bf(v1.x); r[5] = f2bf(v1.y); r[6] = f2bf(v1.z); r[7] = f2bf(v1.w);
    *(uint4*)&xb[base] = *(const uint4*)r;
}

// W [K=256, N=256] f32 -> Wt [n][k] bf16 (transposed, k-contiguous)
__global__ __launch_bounds__(256) void convert_w_kernel(
    const float* __restrict__ W, unsigned short* __restrict__ Wt)
{
    const int n = blockIdx.x;       // 256 blocks
    const int k = threadIdx.x;      // 256 threads
    Wt[n * D_FEAT + k] = f2bf(W[k * D_FEAT + n]);
}

// ---------------------------------------------------------------------------
// Pass 1: per-(bucket, blk&7) counts via LDS histogram.
// Edge->block mapping MUST match scatterB_kernel exactly.
// ---------------------------------------------------------------------------
__global__ __launch_bounds__(256) void countB_kernel(
    const int* __restrict__ edge_row, int* __restrict__ bcnt)
{
    __shared__ int h[NBUCK];
    for (int i = threadIdx.x; i < NBUCK; i += 256) h[i] = 0;
    __syncthreads();
    const int b = blockIdx.x;
    const int start = b * CHUNK;
    const int end   = start + CHUNK;            // exact: CHUNK*CB_BLOCKS == TOT_E
    for (int i = start + threadIdx.x; i < end; i += 256) {
        const int g = i / E_EDGES;
        const int seg = g * N_NODES + edge_row[i];
        atomicAdd(&h[seg >> 7], 1);
    }
    __syncthreads();
    const int sub = b & 7;
    for (int i = threadIdx.x; i < NBUCK; i += 256) {
        const int c = h[i];
        if (c) atomicAdd(&bcnt[i * 8 + sub], c);
    }
}

// ---------------------------------------------------------------------------
// Pass 2: single-block exclusive scan of NSB sub-bucket counts.
// Writes bofs[] (read-only starts) and bcur[] (scatter cursors).
// ---------------------------------------------------------------------------
__global__ __launch_bounds__(SC_T) void scanB_kernel(
    const int* __restrict__ bcnt, int* __restrict__ bofs, int* __restrict__ bcur)
{
    __shared__ int sh[SC_T];
    const int t = threadIdx.x;
    int loc[SC_PER];
    int sum = 0;
    #pragma unroll
    for (int k = 0; k < SC_PER; ++k) {
        const int idx = t * SC_PER + k;
        const int v = (idx < NSB) ? bcnt[idx] : 0;
        loc[k] = sum;
        sum += v;
    }
    sh[t] = sum;
    __syncthreads();
    for (int off = 1; off < SC_T; off <<= 1) {
        const int add = (t >= off) ? sh[t - off] : 0;
        __syncthreads();
        sh[t] += add;
        __syncthreads();
    }
    const int base = sh[t] - sum;               // exclusive offset of this thread
    #pragma unroll
    for (int k = 0; k < SC_PER; ++k) {
        const int idx = t * SC_PER + k;
        if (idx < NSB) {
            const int o = base + loc[k];
            bofs[idx] = o;
            bcur[idx] = o;
        }
    }
    if (t == 0) bofs[NSB] = TOT_E;
}

// ---------------------------------------------------------------------------
// Pass 3: bucket-scatter. pos from per-(bucket, blk&7) cursor -> all writers
// of a sub-bucket frontier sit on one XCD (blockIdx%8 round-robin) -> L2
// merges the 8B stores into full-line writebacks.
// Payload packs {col (18b) | seg_local (7b) << 18, val_bits}.
// ---------------------------------------------------------------------------
__global__ __launch_bounds__(256) void scatterB_kernel(
    const int* __restrict__ edge_row, const int* __restrict__ edge_col,
    const float* __restrict__ edge_val, int* __restrict__ bcur,
    int2* __restrict__ ep)
{
    const int b = blockIdx.x;
    const int start = b * CHUNK;
    const int end   = start + CHUNK;
    const int sub = b & 7;
    for (int i = start + threadIdx.x; i < end; i += 256) {
        const int g = i / E_EDGES;
        const int seg = g * N_NODES + edge_row[i];
        const int bk = seg >> 7;
        const int local = seg & (BSEG - 1);
        const int pos = atomicAdd(&bcur[bk * 8 + sub], 1);
        ep[pos] = make_int2(edge_col[i] | (local << 18), __float_as_int(edge_val[i]));
    }
}

// ---------------------------------------------------------------------------
// SpMM, bucket-parallel: one workgroup per bucket (128 segs x 64 lanes f32
// LDS accumulator, 32KB). Edges of the bucket are wave-partitioned; gathers
// are 128B contiguous per edge; LDS f32 atomics are lane-contiguous
// (conflict-free). Output written coalesced, full lines.
// ---------------------------------------------------------------------------
__global__ __launch_bounds__(256) void spmm_bucket_kernel(
    const unsigned short* __restrict__ xb, const int2* __restrict__ ep,
    const int* __restrict__ bofs, unsigned short* __restrict__ tmpb)
{
    __shared__ float acc[BSEG * 64];            // 32 KB
    const int b = blockIdx.x;
    const int tid = threadIdx.x;
    for (int i = tid; i < BSEG * 64; i += 256) acc[i] = 0.f;
    __syncthreads();

    const int s = bofs[b * 8];
    const int e = bofs[(b + 1) * 8];
    const int seg0 = b * BSEG;
    const int g0 = seg0 / N_NODES;
    const int bnd = (g0 + 1) * N_NODES;         // group boundary within bucket
    const int wid = tid >> 6, lane = tid & 63;

    const int n = e - s;
    const int per = (n + 3) >> 2;
    const int ws = s + wid * per;
    const int we = min(ws + per, e);

    int j = ws;
    for (; j + 4 <= we; j += 4) {
        const int2 p0 = ep[j + 0];
        const int2 p1 = ep[j + 1];
        const int2 p2 = ep[j + 2];
        const int2 p3 = ep[j + 3];
        const int c0 = p0.x & 0x3FFFF, l0 = p0.x >> 18;
        const int c1 = p1.x & 0x3FFFF, l1 = p1.x >> 18;
        const int c2 = p2.x & 0x3FFFF, l2 = p2.x >> 18;
        const int c3 = p3.x & 0x3FFFF, l3 = p3.x >> 18;
        const int ga0 = (seg0 + l0 >= bnd) ? (g0 + 1) * DG : g0 * DG;
        const int ga1 = (seg0 + l1 >= bnd) ? (g0 + 1) * DG : g0 * DG;
        const int ga2 = (seg0 + l2 >= bnd) ? (g0 + 1) * DG : g0 * DG;
        const int ga3 = (seg0 + l3 >= bnd) ? (g0 + 1) * DG : g0 * DG;
        const float x0 = bf2f(xb[c0 * D_FEAT + ga0 + lane]);
        const float x1 = bf2f(xb[c1 * D_FEAT + ga1 + lane]);
        const float x2 = bf2f(xb[c2 * D_FEAT + ga2 + lane]);
        const float x3 = bf2f(xb[c3 * D_FEAT + ga3 + lane]);
        atomicAdd(&acc[l0 * 64 + lane], __int_as_float(p0.y) * x0);
        atomicAdd(&acc[l1 * 64 + lane], __int_as_float(p1.y) * x1);
        atomicAdd(&acc[l2 * 64 + lane], __int_as_float(p2.y) * x2);
        atomicAdd(&acc[l3 * 64 + lane], __int_as_float(p3.y) * x3);
    }
    for (; j < we; ++j) {
        const int2 p = ep[j];
        const int c = p.x & 0x3FFFF, l = p.x >> 18;
        const int ga = (seg0 + l >= bnd) ? (g0 + 1) * DG : g0 * DG;
        const float xv = bf2f(xb[c * D_FEAT + ga + lane]);
        atomicAdd(&acc[l * 64 + lane], __int_as_float(p.y) * xv);
    }
    __syncthreads();

    const int nseg = min(BSEG, M_SEG - seg0);
    for (int r = wid; r < nseg; r += 4) {
        const int seg = seg0 + r;
        const int g = (seg >= bnd) ? (g0 + 1) : g0;
        const int row = seg - g * N_NODES;
        tmpb[row * D_FEAT + g * DG + lane] = f2bf(acc[r * 64 + lane]);
    }
}

// ---------------------------------------------------------------------------
// MFMA GEMM: C[M,256] = tmp_bf @ W + bias.  A: [M_PAD,256] bf16 row-major,
// Bt: [256,256] bf16 n-major/k-contiguous. 128x128 tile, BK=32, 4 waves.
// ---------------------------------------------------------------------------
#define TBK 32
#define LDP 40   // padded LDS row (ushorts): 80B stride spreads all 32 banks

__global__ __launch_bounds__(256) void gemm_mfma_kernel(
    const unsigned short* __restrict__ A, const unsigned short* __restrict__ Bt,
    const float* __restrict__ bias, float* __restrict__ C)
{
    __shared__ unsigned short As[128][LDP];   // 10 KB
    __shared__ unsigned short Bs[128][LDP];   // 10 KB

    const int tid = threadIdx.x;
    const int wid = tid >> 6, lane = tid & 63;
    const int wm = (wid & 1) * 64, wn = (wid >> 1) * 64;
    const int lm = lane & 15, lq = lane >> 4;
    const int row0 = blockIdx.x * 128, col0 = blockIdx.y * 128;

    f32x4 acc[4][4] = {};

    for (int k0 = 0; k0 < D_FEAT; k0 += TBK) {
        // A tile: 128 rows x 32 k; 64B/row = 4 x 16B chunks; 2 chunks/thread
        #pragma unroll
        for (int l = 0; l < 2; ++l) {
            const int chunk = tid + l * 256;     // 0..511
            const int r = chunk >> 2;
            const int c = (chunk & 3) * 8;
            uint4 v = make_uint4(0u, 0u, 0u, 0u);
            const int gr = row0 + r;
            if (gr < N_NODES)
                v = *(const uint4*)&A[(long long)gr * D_FEAT + k0 + c];
            *(uint4*)&As[r][c] = v;
        }
        #pragma unroll
        for (int l = 0; l < 2; ++l) {
            const int chunk = tid + l * 256;
            const int r = chunk >> 2;
            const int c = (chunk & 3) * 8;
            *(uint4*)&Bs[r][c] =
                *(const uint4*)&Bt[(long long)(col0 + r) * D_FEAT + k0 + c];
        }
        __syncthreads();

        bf16x8 af[4], bfr[4];
        #pragma unroll
        for (int mi = 0; mi < 4; ++mi)
            af[mi] = *(const bf16x8*)&As[wm + mi * 16 + lm][lq * 8];
        #pragma unroll
        for (int ni = 0; ni < 4; ++ni)
            bfr[ni] = *(const bf16x8*)&Bs[wn + ni * 16 + lm][lq * 8];
        #pragma unroll
        for (int mi = 0; mi < 4; ++mi)
            #pragma unroll
            for (int ni = 0; ni < 4; ++ni)
                acc[mi][ni] = __builtin_amdgcn_mfma_f32_16x16x32_bf16(
                    af[mi], bfr[ni], acc[mi][ni], 0, 0, 0);
        __syncthreads();
    }

    // D layout: col = lane&15, row = (lane>>4)*4 + reg
    #pragma unroll
    for (int mi = 0; mi < 4; ++mi) {
        #pragma unroll
        for (int ni = 0; ni < 4; ++ni) {
            const int n = col0 + wn + ni * 16 + lm;
            const float b = bias[n];
            #pragma unroll
            for (int r = 0; r < 4; ++r) {
                const int m = row0 + wm + mi * 16 + lq * 4 + r;
                if (m < N_NODES)
                    C[(long long)m * D_FEAT + n] = acc[mi][ni][r] + b;
            }
        }
    }
}

// ---------------------------------------------------------------------------
// Fallback path (atomic f32 spmm + f32 GEMM) — only if ws too small.
// ---------------------------------------------------------------------------
__global__ __launch_bounds__(256) void spmm_scatter_kernel(
    const float* __restrict__ x, const int* __restrict__ edge_row,
    const int* __restrict__ edge_col, const float* __restrict__ edge_val,
    float* __restrict__ tmp)
{
    const long long gtid = (long long)blockIdx.x * blockDim.x + threadIdx.x;
    const int wave = (int)(gtid >> 6);
    const int lane = threadIdx.x & 63;
    if (wave >= TOT_E) return;
    const int g = wave / E_EDGES;
    const int row = edge_row[wave];
    const int col = edge_col[wave];
    const float val = edge_val[wave];
    atomicAdd(&tmp[(long long)row * D_FEAT + g * DG + lane],
              val * x[(long long)col * D_FEAT + g * DG + lane]);
}

__global__ __launch_bounds__(256) void gemm_bias_kernel(
    const float* __restrict__ A, const float* __restrict__ W,
    const float* __restrict__ bias, float* __restrict__ C)
{
    __shared__ float Asf[64][68];
    __shared__ float Wsf[64][68];
    const int tid = threadIdx.x;
    const int tx = tid & 15, ty = tid >> 4;
    const int row0 = blockIdx.x * 64, col0 = blockIdx.y * 64;
    float acc[4][4] = {};
    for (int k0 = 0; k0 < D_FEAT; k0 += 64) {
        #pragma unroll
        for (int l = 0; l < 4; ++l) {
            const int linear = tid + l * 256;
            const int ar = linear >> 4, ac = (linear & 15) << 2;
            float4 v = make_float4(0.f, 0.f, 0.f, 0.f);
            const int gr = row0 + ar;
            if (gr < N_NODES) v = *(const float4*)&A[(long long)gr * D_FEAT + k0 + ac];
            Asf[ac + 0][ar] = v.x; Asf[ac + 1][ar] = v.y;
            Asf[ac + 2][ar] = v.z; Asf[ac + 3][ar] = v.w;
        }
        #pragma unroll
        for (int l = 0; l < 4; ++l) {
            const int linear = tid + l * 256;
            const int wr = linear >> 4, wc = (linear & 15) << 2;
            *(float4*)&Wsf[wr][wc] =
                *(const float4*)&W[(long long)(k0 + wr) * D_FEAT + col0 + wc];
        }
        __syncthreads();
        #pragma unroll
        for (int k = 0; k < 64; ++k) {
            const float4 a4 = *(const float4*)&Asf[k][ty * 4];
            const float4 b4 = *(const float4*)&Wsf[k][tx * 4];
            const float a[4] = {a4.x, a4.y, a4.z, a4.w};
            const float b[4] = {b4.x, b4.y, b4.z, b4.w};
            #pragma unroll
            for (int i = 0; i < 4; ++i)
                #pragma unroll
                for (int j = 0; j < 4; ++j) acc[i][j] += a[i] * b[j];
        }
        __syncthreads();
    }
    const float4 b4 = *(const float4*)&bias[col0 + tx * 4];
    #pragma unroll
    for (int i = 0; i < 4; ++i) {
        const int gr = row0 + ty * 4 + i;
        if (gr >= N_NODES) continue;
        float4 v;
        v.x = acc[i][0] + b4.x; v.y = acc[i][1] + b4.y;
        v.z = acc[i][2] + b4.z; v.w = acc[i][3] + b4.w;
        *(float4*)&C[(long long)gr * D_FEAT + col0 + tx * 4] = v;
    }
}

// ---------------------------------------------------------------------------
extern "C" void kernel_launch(void* const* d_in, const int* in_sizes, int n_in,
                              void* d_out, int out_size, void* d_ws, size_t ws_size,
                              hipStream_t stream)
{
    const float* x        = (const float*)d_in[0];
    const int*   edge_row = (const int*)d_in[1];
    const int*   edge_col = (const int*)d_in[2];
    const float* edge_val = (const float*)d_in[3];
    const float* weight   = (const float*)d_in[4];
    const float* bias     = (const float*)d_in[5];
    float* out = (float*)d_out;

    char* p = (char*)d_ws;
    auto alloc = [&](size_t bytes) {
        char* r = p;
        p += (bytes + 255) & ~(size_t)255;
        return r;
    };
    unsigned short* xb   = (unsigned short*)alloc((size_t)N_NODES * D_FEAT * 2); // 25.6 MB
    unsigned short* tmpb = (unsigned short*)alloc((size_t)M_PAD * D_FEAT * 2);   // 25.6 MB
    unsigned short* Wt   = (unsigned short*)alloc((size_t)D_FEAT * D_FEAT * 2);  // 128 KB
    int2* ep  = (int2*)alloc((size_t)TOT_E * sizeof(int2));                      // 25.6 MB
    int* bcnt = (int*)alloc((size_t)NSB * sizeof(int));                          // 50 KB
    int* bofs = (int*)alloc((size_t)(NSB + 1) * sizeof(int));                    // 50 KB
    int* bcur = (int*)alloc((size_t)NSB * sizeof(int));                          // 50 KB
    const size_t needed = (size_t)(p - (char*)d_ws);

    if (ws_size >= needed) {
        hipMemsetAsync(bcnt, 0, (size_t)NSB * sizeof(int), stream);
        convert_x_kernel<<<(N_NODES * D_FEAT / 8 + 255) / 256, 256, 0, stream>>>(x, xb);
        convert_w_kernel<<<D_FEAT, D_FEAT, 0, stream>>>(weight, Wt);
        countB_kernel<<<CB_BLOCKS, 256, 0, stream>>>(edge_row, bcnt);
        scanB_kernel<<<1, SC_T, 0, stream>>>(bcnt, bofs, bcur);
        scatterB_kernel<<<CB_BLOCKS, 256, 0, stream>>>(
            edge_row, edge_col, edge_val, bcur, ep);
        spmm_bucket_kernel<<<NBUCK, 256, 0, stream>>>(xb, ep, bofs, tmpb);
        dim3 grid(M_PAD / 128, D_FEAT / 128);
        gemm_mfma_kernel<<<grid, 256, 0, stream>>>(tmpb, Wt, bias, out);
    } else {
        float* tmp = (float*)d_ws;
        hipMemsetAsync(tmp, 0, (size_t)N_NODES * D_FEAT * sizeof(float), stream);
        const long long total_threads = (long long)TOT_E * 64;
        spmm_scatter_kernel<<<(int)((total_threads + 255) / 256), 256, 0, stream>>>(
            x, edge_row, edge_col, edge_val, tmp);
        dim3 grid2((N_NODES + 63) / 64, D_FEAT / 64);
        gemm_bias_kernel<<<grid2, 256, 0, stream>>>(tmp, weight, bias, out);
    }
}

// Round 3
// 395.699 us; speedup vs baseline: 4.0078x; 4.0078x over previous
//
#include <hip/hip_runtime.h>
#include <hip/hip_bf16.h>

#define N_NODES 50000
#define D_FEAT  256
#define G_GROUPS 4
#define E_EDGES 800000
#define DG      64
#define M_SEG   (G_GROUPS * N_NODES)        // 200000 segments
#define TOT_E   (G_GROUPS * E_EDGES)        // 3200000 edges
#define M_PAD   50048                       // 391 * 128

// two-level counting sort geometry
#define SEGB      512                        // segments per coarse bucket (2^9)
#define NB1       391                        // ceil(M_SEG / SEGB)
#define CA_BLOCKS 400
#define CHA       8000                       // 400 * 8000 == TOT_E exact

typedef short bf16x8 __attribute__((ext_vector_type(8)));   // 8 bf16 (4 VGPRs)
typedef float f32x4  __attribute__((ext_vector_type(4)));

__device__ __forceinline__ unsigned short f2bf(float f) {
    unsigned int u = __float_as_uint(f);
    u += 0x7FFF + ((u >> 16) & 1);          // RNE
    return (unsigned short)(u >> 16);
}
__device__ __forceinline__ float bf2f(unsigned short h) {
    return __uint_as_float((unsigned int)h << 16);
}

// ---------------------------------------------------------------------------
// x (f32 [N,256]) -> x_bf (bf16). 8 elems / thread.
// ---------------------------------------------------------------------------
__global__ __launch_bounds__(256) void convert_x_kernel(
    const float* __restrict__ x, unsigned short* __restrict__ xb)
{
    const long long base = ((long long)blockIdx.x * 256 + threadIdx.x) * 8;
    if (base >= (long long)N_NODES * D_FEAT) return;
    const float4 v0 = *(const float4*)&x[base];
    const float4 v1 = *(const float4*)&x[base + 4];
    unsigned short r[8];
    r[0] = f2bf(v0.x); r[1] = f2bf(v0.y); r[2] = f2bf(v0.z); r[3] = f2bf(v0.w);
    r[4] = f2bf(v1.x); r[5] = f2bf(v1.y); r[6] = f2bf(v1.z); r[7] = f2bf(v1.w);
    *(uint4*)&xb[base] = *(const uint4*)r;
}

// W [K=256, N=256] f32 -> Wt [n][k] bf16 (transposed, k-contiguous)
__global__ __launch_bounds__(256) void convert_w_kernel(
    const float* __restrict__ W, unsigned short* __restrict__ Wt)
{
    const int n = blockIdx.x;       // 256 blocks
    const int k = threadIdx.x;      // 256 threads
    Wt[n * D_FEAT + k] = f2bf(W[k * D_FEAT + n]);
}

// ---------------------------------------------------------------------------
// Pass A1: global per-coarse-bucket counts (LDS-staged histogram).
// ---------------------------------------------------------------------------
__global__ __launch_bounds__(256) void countA_kernel(
    const int* __restrict__ edge_row, int* __restrict__ cntA)
{
    __shared__ int h[NB1];
    const int t = threadIdx.x;
    for (int i = t; i < NB1; i += 256) h[i] = 0;
    __syncthreads();
    const int start = blockIdx.x * CHA;
    const int end   = start + CHA;
    for (int i = start + t; i < end; i += 256) {
        const int g = i / E_EDGES;
        const int seg = g * N_NODES + edge_row[i];
        atomicAdd(&h[seg >> 9], 1);
    }
    __syncthreads();
    for (int i = t; i < NB1; i += 256)
        if (h[i]) atomicAdd(&cntA[i], h[i]);
}

// ---------------------------------------------------------------------------
// Pass A2: single-block exclusive scan of the 391 bucket counts.
// Writes ofsA[] (bucket region starts, 392 entries), curA[] (reserve
// cursors), and ofs[M_SEG] sentinel.
// ---------------------------------------------------------------------------
__global__ __launch_bounds__(256) void scanA_kernel(
    const int* __restrict__ cntA, int* __restrict__ ofsA,
    int* __restrict__ curA, int* __restrict__ ofs)
{
    __shared__ int ssum[256];
    const int t = threadIdx.x;
    const int i0 = 2 * t, i1 = 2 * t + 1;
    const int v0 = (i0 < NB1) ? cntA[i0] : 0;
    const int v1 = (i1 < NB1) ? cntA[i1] : 0;
    ssum[t] = v0 + v1;
    __syncthreads();
    for (int off = 1; off < 256; off <<= 1) {
        const int add = (t >= off) ? ssum[t - off] : 0;
        __syncthreads();
        ssum[t] += add;
        __syncthreads();
    }
    const int eb = ssum[t] - (v0 + v1);       // exclusive base of pair
    if (i0 < NB1) { ofsA[i0] = eb;      curA[i0] = eb; }
    if (i1 < NB1) { ofsA[i1] = eb + v0; curA[i1] = eb + v0; }
    if (t == 255) {
        ofsA[NB1] = ssum[255];                // == TOT_E
        ofs[M_SEG] = ssum[255];
    }
}

// ---------------------------------------------------------------------------
// Pass A3: coarse scatter. Each block histograms its chunk, reserves one
// contiguous region per bucket with a single global atomic, then fills its
// own (private, L2-resident) reserved chunks -> full-line writebacks.
// Payload packs {col (16b) | seg_local (9b) << 16, val_bits}.
// ---------------------------------------------------------------------------
__global__ __launch_bounds__(256) void scatterA_kernel(
    const int* __restrict__ edge_row, const int* __restrict__ edge_col,
    const float* __restrict__ edge_val, int* __restrict__ curA,
    int2* __restrict__ epA)
{
    __shared__ int hist[NB1];
    __shared__ int gcur[NB1];
    const int t = threadIdx.x;
    for (int i = t; i < NB1; i += 256) hist[i] = 0;
    __syncthreads();
    const int start = blockIdx.x * CHA;
    const int end   = start + CHA;
    for (int i = start + t; i < end; i += 256) {
        const int g = i / E_EDGES;
        const int seg = g * N_NODES + edge_row[i];
        atomicAdd(&hist[seg >> 9], 1);
    }
    __syncthreads();
    for (int i = t; i < NB1; i += 256)
        gcur[i] = hist[i] ? atomicAdd(&curA[i], hist[i]) : 0;
    __syncthreads();
    for (int i = start + t; i < end; i += 256) {
        const int g = i / E_EDGES;
        const int seg = g * N_NODES + edge_row[i];
        const int bk = seg >> 9;
        const int sl = seg & (SEGB - 1);
        const int pos = atomicAdd(&gcur[bk], 1);
        epA[pos] = make_int2(edge_col[i] | (sl << 16), __float_as_int(edge_val[i]));
    }
}

// ---------------------------------------------------------------------------
// Pass B: fine sort within each coarse bucket. One block per bucket:
// LDS histogram over 512 seg_locals -> scan -> per-segment CSR starts
// (written to ofs[], globally seg-ordered) -> scatter into the bucket's
// private ~64KB region of epB (L2-resident, lines merge).
// ---------------------------------------------------------------------------
__global__ __launch_bounds__(256) void sortB_kernel(
    const int2* __restrict__ epA, const int* __restrict__ ofsA,
    int2* __restrict__ epB, int* __restrict__ ofs)
{
    __shared__ int hist[SEGB];
    __shared__ int lofs[SEGB];
    __shared__ int ssum[256];
    const int b = blockIdx.x;
    const int t = threadIdx.x;
    const int s = ofsA[b], e = ofsA[b + 1];
    hist[t] = 0; hist[t + 256] = 0;
    __syncthreads();
    for (int j = s + t; j < e; j += 256) {
        const int sl = ((unsigned)epA[j].x) >> 16;
        atomicAdd(&hist[sl], 1);
    }
    __syncthreads();
    // pair-wise exclusive scan of 512 entries with 256 threads
    const int a0 = hist[2 * t], a1 = hist[2 * t + 1];
    ssum[t] = a0 + a1;
    __syncthreads();
    for (int off = 1; off < 256; off <<= 1) {
        const int add = (t >= off) ? ssum[t - off] : 0;
        __syncthreads();
        ssum[t] += add;
        __syncthreads();
    }
    const int eb = ssum[t] - (a0 + a1);
    lofs[2 * t]     = eb;
    lofs[2 * t + 1] = eb + a0;
    __syncthreads();
    // global CSR starts for this bucket (coalesced)
    const int seg0 = b * SEGB;
    const int nseg = min(SEGB, M_SEG - seg0);
    for (int sl = t; sl < nseg; sl += 256) ofs[seg0 + sl] = s + lofs[sl];
    __syncthreads();
    // scatter within bucket; lofs doubles as running cursor
    for (int j = s + t; j < e; j += 256) {
        const int2 p = epA[j];
        const int sl = ((unsigned)p.x) >> 16;
        const int pos = atomicAdd(&lofs[sl], 1);
        epB[s + pos] = make_int2(p.x & 0xFFFF, p.y);
    }
}

// ---------------------------------------------------------------------------
// CSR gather SpMM: one wave per (g,row); contiguous edge run, no pointer
// chase. Unroll-4 gathers in flight; bf16 gathers, f32 acc, bf16 store.
// ---------------------------------------------------------------------------
__global__ __launch_bounds__(256) void spmm_csr_kernel(
    const unsigned short* __restrict__ xb, const int2* __restrict__ ep,
    const int* __restrict__ ofs, unsigned short* __restrict__ tmpb)
{
    const int w = (blockIdx.x * 256 + threadIdx.x) >> 6;   // segment, exact
    const int lane = threadIdx.x & 63;
    const int g = w / N_NODES;
    const int row = w - g * N_NODES;

    const unsigned short* __restrict__ xcol = xb + g * DG + lane;

    const int s = ofs[w];
    const int e = ofs[w + 1];

    float acc = 0.f;
    int j = s;
    for (; j + 4 <= e; j += 4) {
        const int2 p0 = ep[j + 0];
        const int2 p1 = ep[j + 1];
        const int2 p2 = ep[j + 2];
        const int2 p3 = ep[j + 3];
        acc += __int_as_float(p0.y) * bf2f(xcol[p0.x * D_FEAT]);
        acc += __int_as_float(p1.y) * bf2f(xcol[p1.x * D_FEAT]);
        acc += __int_as_float(p2.y) * bf2f(xcol[p2.x * D_FEAT]);
        acc += __int_as_float(p3.y) * bf2f(xcol[p3.x * D_FEAT]);
    }
    for (; j < e; ++j) {
        const int2 p = ep[j];
        acc += __int_as_float(p.y) * bf2f(xcol[p.x * D_FEAT]);
    }
    tmpb[(long long)row * D_FEAT + g * DG + lane] = f2bf(acc);
}

// ---------------------------------------------------------------------------
// MFMA GEMM: C[M,256] = tmp_bf @ W + bias.  A: [M_PAD,256] bf16 row-major,
// Bt: [256,256] bf16 n-major/k-contiguous. 128x128 tile, BK=32, 4 waves.
// ---------------------------------------------------------------------------
#define TBK 32
#define LDP 40   // padded LDS row (ushorts): 80B stride spreads all 32 banks

__global__ __launch_bounds__(256) void gemm_mfma_kernel(
    const unsigned short* __restrict__ A, const unsigned short* __restrict__ Bt,
    const float* __restrict__ bias, float* __restrict__ C)
{
    __shared__ unsigned short As[128][LDP];   // 10 KB
    __shared__ unsigned short Bs[128][LDP];   // 10 KB

    const int tid = threadIdx.x;
    const int wid = tid >> 6, lane = tid & 63;
    const int wm = (wid & 1) * 64, wn = (wid >> 1) * 64;
    const int lm = lane & 15, lq = lane >> 4;
    const int row0 = blockIdx.x * 128, col0 = blockIdx.y * 128;

    f32x4 acc[4][4] = {};

    for (int k0 = 0; k0 < D_FEAT; k0 += TBK) {
        // A tile: 128 rows x 32 k; 64B/row = 4 x 16B chunks; 2 chunks/thread
        #pragma unroll
        for (int l = 0; l < 2; ++l) {
            const int chunk = tid + l * 256;     // 0..511
            const int r = chunk >> 2;
            const int c = (chunk & 3) * 8;
            uint4 v = make_uint4(0u, 0u, 0u, 0u);
            const int gr = row0 + r;
            if (gr < N_NODES)
                v = *(const uint4*)&A[(long long)gr * D_FEAT + k0 + c];
            *(uint4*)&As[r][c] = v;
        }
        #pragma unroll
        for (int l = 0; l < 2; ++l) {
            const int chunk = tid + l * 256;
            const int r = chunk >> 2;
            const int c = (chunk & 3) * 8;
            *(uint4*)&Bs[r][c] =
                *(const uint4*)&Bt[(long long)(col0 + r) * D_FEAT + k0 + c];
        }
        __syncthreads();

        bf16x8 af[4], bfr[4];
        #pragma unroll
        for (int mi = 0; mi < 4; ++mi)
            af[mi] = *(const bf16x8*)&As[wm + mi * 16 + lm][lq * 8];
        #pragma unroll
        for (int ni = 0; ni < 4; ++ni)
            bfr[ni] = *(const bf16x8*)&Bs[wn + ni * 16 + lm][lq * 8];
        #pragma unroll
        for (int mi = 0; mi < 4; ++mi)
            #pragma unroll
            for (int ni = 0; ni < 4; ++ni)
                acc[mi][ni] = __builtin_amdgcn_mfma_f32_16x16x32_bf16(
                    af[mi], bfr[ni], acc[mi][ni], 0, 0, 0);
        __syncthreads();
    }

    // D layout: col = lane&15, row = (lane>>4)*4 + reg
    #pragma unroll
    for (int mi = 0; mi < 4; ++mi) {
        #pragma unroll
        for (int ni = 0; ni < 4; ++ni) {
            const int n = col0 + wn + ni * 16 + lm;
            const float b = bias[n];
            #pragma unroll
            for (int r = 0; r < 4; ++r) {
                const int m = row0 + wm + mi * 16 + lq * 4 + r;
                if (m < N_NODES)
                    C[(long long)m * D_FEAT + n] = acc[mi][ni][r] + b;
            }
        }
    }
}

// ---------------------------------------------------------------------------
// Fallback path (atomic f32 spmm + f32 GEMM) — only if ws too small.
// ---------------------------------------------------------------------------
__global__ __launch_bounds__(256) void spmm_scatter_kernel(
    const float* __restrict__ x, const int* __restrict__ edge_row,
    const int* __restrict__ edge_col, const float* __restrict__ edge_val,
    float* __restrict__ tmp)
{
    const long long gtid = (long long)blockIdx.x * blockDim.x + threadIdx.x;
    const int wave = (int)(gtid >> 6);
    const int lane = threadIdx.x & 63;
    if (wave >= TOT_E) return;
    const int g = wave / E_EDGES;
    const int row = edge_row[wave];
    const int col = edge_col[wave];
    const float val = edge_val[wave];
    atomicAdd(&tmp[(long long)row * D_FEAT + g * DG + lane],
              val * x[(long long)col * D_FEAT + g * DG + lane]);
}

__global__ __launch_bounds__(256) void gemm_bias_kernel(
    const float* __restrict__ A, const float* __restrict__ W,
    const float* __restrict__ bias, float* __restrict__ C)
{
    __shared__ float Asf[64][68];
    __shared__ float Wsf[64][68];
    const int tid = threadIdx.x;
    const int tx = tid & 15, ty = tid >> 4;
    const int row0 = blockIdx.x * 64, col0 = blockIdx.y * 64;
    float acc[4][4] = {};
    for (int k0 = 0; k0 < D_FEAT; k0 += 64) {
        #pragma unroll
        for (int l = 0; l < 4; ++l) {
            const int linear = tid + l * 256;
            const int ar = linear >> 4, ac = (linear & 15) << 2;
            float4 v = make_float4(0.f, 0.f, 0.f, 0.f);
            const int gr = row0 + ar;
            if (gr < N_NODES) v = *(const float4*)&A[(long long)gr * D_FEAT + k0 + ac];
            Asf[ac + 0][ar] = v.x; Asf[ac + 1][ar] = v.y;
            Asf[ac + 2][ar] = v.z; Asf[ac + 3][ar] = v.w;
        }
        #pragma unroll
        for (int l = 0; l < 4; ++l) {
            const int linear = tid + l * 256;
            const int wr = linear >> 4, wc = (linear & 15) << 2;
            *(float4*)&Wsf[wr][wc] =
                *(const float4*)&W[(long long)(k0 + wr) * D_FEAT + col0 + wc];
        }
        __syncthreads();
        #pragma unroll
        for (int k = 0; k < 64; ++k) {
            const float4 a4 = *(const float4*)&Asf[k][ty * 4];
            const float4 b4 = *(const float4*)&Wsf[k][tx * 4];
            const float a[4] = {a4.x, a4.y, a4.z, a4.w};
            const float b[4] = {b4.x, b4.y, b4.z, b4.w};
            #pragma unroll
            for (int i = 0; i < 4; ++i)
                #pragma unroll
                for (int j = 0; j < 4; ++j) acc[i][j] += a[i] * b[j];
        }
        __syncthreads();
    }
    const float4 b4 = *(const float4*)&bias[col0 + tx * 4];
    #pragma unroll
    for (int i = 0; i < 4; ++i) {
        const int gr = row0 + ty * 4 + i;
        if (gr >= N_NODES) continue;
        float4 v;
        v.x = acc[i][0] + b4.x; v.y = acc[i][1] + b4.y;
        v.z = acc[i][2] + b4.z; v.w = acc[i][3] + b4.w;
        *(float4*)&C[(long long)gr * D_FEAT + col0 + tx * 4] = v;
    }
}

// ---------------------------------------------------------------------------
extern "C" void kernel_launch(void* const* d_in, const int* in_sizes, int n_in,
                              void* d_out, int out_size, void* d_ws, size_t ws_size,
                              hipStream_t stream)
{
    const float* x        = (const float*)d_in[0];
    const int*   edge_row = (const int*)d_in[1];
    const int*   edge_col = (const int*)d_in[2];
    const float* edge_val = (const float*)d_in[3];
    const float* weight   = (const float*)d_in[4];
    const float* bias     = (const float*)d_in[5];
    float* out = (float*)d_out;

    char* p = (char*)d_ws;
    auto alloc = [&](size_t bytes) {
        char* r = p;
        p += (bytes + 255) & ~(size_t)255;
        return r;
    };
    unsigned short* xb   = (unsigned short*)alloc((size_t)N_NODES * D_FEAT * 2); // 25.6 MB
    unsigned short* tmpb = (unsigned short*)alloc((size_t)M_PAD * D_FEAT * 2);   // 25.6 MB
    unsigned short* Wt   = (unsigned short*)alloc((size_t)D_FEAT * D_FEAT * 2);  // 128 KB
    int2* epB = (int2*)alloc((size_t)TOT_E * sizeof(int2));                      // 25.6 MB
    int* cntA = (int*)alloc((size_t)NB1 * sizeof(int));
    int* ofsA = (int*)alloc((size_t)(NB1 + 1) * sizeof(int));
    int* curA = (int*)alloc((size_t)NB1 * sizeof(int));
    int* ofs  = (int*)alloc((size_t)(M_SEG + 1) * sizeof(int));                  // 800 KB
    const size_t needed = (size_t)(p - (char*)d_ws);

    // epA aliases tmpb: TOT_E*8 = 25,600,000 B <= M_PAD*256*2 = 25,624,576 B.
    // epA is dead before spmm_csr writes tmpb (stream-ordered).
    int2* epA = (int2*)tmpb;

    if (ws_size >= needed) {
        hipMemsetAsync(cntA, 0, (size_t)NB1 * sizeof(int), stream);
        convert_x_kernel<<<(N_NODES * D_FEAT / 8 + 255) / 256, 256, 0, stream>>>(x, xb);
        convert_w_kernel<<<D_FEAT, D_FEAT, 0, stream>>>(weight, Wt);
        countA_kernel<<<CA_BLOCKS, 256, 0, stream>>>(edge_row, cntA);
        scanA_kernel<<<1, 256, 0, stream>>>(cntA, ofsA, curA, ofs);
        scatterA_kernel<<<CA_BLOCKS, 256, 0, stream>>>(
            edge_row, edge_col, edge_val, curA, epA);
        sortB_kernel<<<NB1, 256, 0, stream>>>(epA, ofsA, epB, ofs);
        spmm_csr_kernel<<<M_SEG * 64 / 256, 256, 0, stream>>>(xb, epB, ofs, tmpb);
        dim3 grid(M_PAD / 128, D_FEAT / 128);
        gemm_mfma_kernel<<<grid, 256, 0, stream>>>(tmpb, Wt, bias, out);
    } else {
        float* tmp = (float*)d_ws;
        hipMemsetAsync(tmp, 0, (size_t)N_NODES * D_FEAT * sizeof(float), stream);
        const long long total_threads = (long long)TOT_E * 64;
        spmm_scatter_kernel<<<(int)((total_threads + 255) / 256), 256, 0, stream>>>(
            x, edge_row, edge_col, edge_val, tmp);
        dim3 grid2((N_NODES + 63) / 64, D_FEAT / 64);
        gemm_bias_kernel<<<grid2, 256, 0, stream>>>(tmp, weight, bias, out);
    }
}

// Round 4
// 359.552 us; speedup vs baseline: 4.4107x; 1.1005x over previous
//
#include <hip/hip_runtime.h>
#include <hip/hip_bf16.h>

#define N_NODES 50000
#define D_FEAT  256
#define G_GROUPS 4
#define E_EDGES 800000
#define DG      64
#define M_SEG   (G_GROUPS * N_NODES)        // 200000 segments
#define TOT_E   (G_GROUPS * E_EDGES)        // 3200000 edges
#define M_PAD   50048                       // 391 * 128

// two-level counting sort geometry
#define SEGB      512                        // segments per coarse bucket (2^9)
#define NB1       391                        // ceil(M_SEG / SEGB)
#define CA_BLOCKS 400
#define CHA       8000                       // 400 * 8000 == TOT_E exact

typedef short bf16x8 __attribute__((ext_vector_type(8)));   // 8 bf16 (4 VGPRs)
typedef float f32x4  __attribute__((ext_vector_type(4)));

__device__ __forceinline__ unsigned short f2bf(float f) {
    unsigned int u = __float_as_uint(f);
    u += 0x7FFF + ((u >> 16) & 1);          // RNE
    return (unsigned short)(u >> 16);
}
__device__ __forceinline__ float bf2f(unsigned short h) {
    return __uint_as_float((unsigned int)h << 16);
}

// ---------------------------------------------------------------------------
// x (f32 [N,256]) -> x_bf (bf16). 8 elems / thread.
// ---------------------------------------------------------------------------
__global__ __launch_bounds__(256) void convert_x_kernel(
    const float* __restrict__ x, unsigned short* __restrict__ xb)
{
    const long long base = ((long long)blockIdx.x * 256 + threadIdx.x) * 8;
    if (base >= (long long)N_NODES * D_FEAT) return;
    const float4 v0 = *(const float4*)&x[base];
    const float4 v1 = *(const float4*)&x[base + 4];
    unsigned short r[8];
    r[0] = f2bf(v0.x); r[1] = f2bf(v0.y); r[2] = f2bf(v0.z); r[3] = f2bf(v0.w);
    r[4] = f2bf(v1.x); r[5] = f2bf(v1.y); r[6] = f2bf(v1.z); r[7] = f2bf(v1.w);
    *(uint4*)&xb[base] = *(const uint4*)r;
}

// W [K=256, N=256] f32 -> Wt [n][k] bf16 (transposed, k-contiguous)
__global__ __launch_bounds__(256) void convert_w_kernel(
    const float* __restrict__ W, unsigned short* __restrict__ Wt)
{
    const int n = blockIdx.x;       // 256 blocks
    const int k = threadIdx.x;      // 256 threads
    Wt[n * D_FEAT + k] = f2bf(W[k * D_FEAT + n]);
}

// ---------------------------------------------------------------------------
// Pass A1: global per-coarse-bucket counts (LDS-staged histogram).
// ---------------------------------------------------------------------------
__global__ __launch_bounds__(256) void countA_kernel(
    const int* __restrict__ edge_row, int* __restrict__ cntA)
{
    __shared__ int h[NB1];
    const int t = threadIdx.x;
    for (int i = t; i < NB1; i += 256) h[i] = 0;
    __syncthreads();
    const int start = blockIdx.x * CHA;
    const int end   = start + CHA;
    for (int i = start + t; i < end; i += 256) {
        const int g = i / E_EDGES;
        const int seg = g * N_NODES + edge_row[i];
        atomicAdd(&h[seg >> 9], 1);
    }
    __syncthreads();
    for (int i = t; i < NB1; i += 256)
        if (h[i]) atomicAdd(&cntA[i], h[i]);
}

// ---------------------------------------------------------------------------
// Pass A2: single-block exclusive scan of the 391 bucket counts.
// Writes ofsA[] (bucket region starts, 392 entries), curA[] (reserve
// cursors), and ofs[M_SEG] sentinel.
// ---------------------------------------------------------------------------
__global__ __launch_bounds__(256) void scanA_kernel(
    const int* __restrict__ cntA, int* __restrict__ ofsA,
    int* __restrict__ curA, int* __restrict__ ofs)
{
    __shared__ int ssum[256];
    const int t = threadIdx.x;
    const int i0 = 2 * t, i1 = 2 * t + 1;
    const int v0 = (i0 < NB1) ? cntA[i0] : 0;
    const int v1 = (i1 < NB1) ? cntA[i1] : 0;
    ssum[t] = v0 + v1;
    __syncthreads();
    for (int off = 1; off < 256; off <<= 1) {
        const int add = (t >= off) ? ssum[t - off] : 0;
        __syncthreads();
        ssum[t] += add;
        __syncthreads();
    }
    const int eb = ssum[t] - (v0 + v1);       // exclusive base of pair
    if (i0 < NB1) { ofsA[i0] = eb;      curA[i0] = eb; }
    if (i1 < NB1) { ofsA[i1] = eb + v0; curA[i1] = eb + v0; }
    if (t == 255) {
        ofsA[NB1] = ssum[255];                // == TOT_E
        ofs[M_SEG] = ssum[255];
    }
}

// ---------------------------------------------------------------------------
// Pass A3: coarse scatter. Each block histograms its chunk, reserves one
// contiguous region per bucket with a single global atomic, then fills its
// own (private, L2-resident) reserved chunks -> full-line writebacks.
// Payload packs {col (16b) | seg_local (9b) << 16, val_bits}.
// ---------------------------------------------------------------------------
__global__ __launch_bounds__(256) void scatterA_kernel(
    const int* __restrict__ edge_row, const int* __restrict__ edge_col,
    const float* __restrict__ edge_val, int* __restrict__ curA,
    int2* __restrict__ epA)
{
    __shared__ int hist[NB1];
    __shared__ int gcur[NB1];
    const int t = threadIdx.x;
    for (int i = t; i < NB1; i += 256) hist[i] = 0;
    __syncthreads();
    const int start = blockIdx.x * CHA;
    const int end   = start + CHA;
    for (int i = start + t; i < end; i += 256) {
        const int g = i / E_EDGES;
        const int seg = g * N_NODES + edge_row[i];
        atomicAdd(&hist[seg >> 9], 1);
    }
    __syncthreads();
    for (int i = t; i < NB1; i += 256)
        gcur[i] = hist[i] ? atomicAdd(&curA[i], hist[i]) : 0;
    __syncthreads();
    for (int i = start + t; i < end; i += 256) {
        const int g = i / E_EDGES;
        const int seg = g * N_NODES + edge_row[i];
        const int bk = seg >> 9;
        const int sl = seg & (SEGB - 1);
        const int pos = atomicAdd(&gcur[bk], 1);
        epA[pos] = make_int2(edge_col[i] | (sl << 16), __float_as_int(edge_val[i]));
    }
}

// ---------------------------------------------------------------------------
// Pass B: fine sort within each coarse bucket. One block per bucket:
// LDS histogram over 512 seg_locals -> scan -> per-segment CSR starts
// (written to ofs[], globally seg-ordered) -> scatter into the bucket's
// private ~64KB region of epB (L2-resident, lines merge).
// epB payload.x is the PRE-SCALED byte offset into xb: col*512 + g*128.
// ---------------------------------------------------------------------------
__global__ __launch_bounds__(256) void sortB_kernel(
    const int2* __restrict__ epA, const int* __restrict__ ofsA,
    int2* __restrict__ epB, int* __restrict__ ofs)
{
    __shared__ int hist[SEGB];
    __shared__ int lofs[SEGB];
    __shared__ int ssum[256];
    const int b = blockIdx.x;
    const int t = threadIdx.x;
    const int s = ofsA[b], e = ofsA[b + 1];
    hist[t] = 0; hist[t + 256] = 0;
    __syncthreads();
    for (int j = s + t; j < e; j += 256) {
        const int sl = ((unsigned)epA[j].x) >> 16;
        atomicAdd(&hist[sl], 1);
    }
    __syncthreads();
    // pair-wise exclusive scan of 512 entries with 256 threads
    const int a0 = hist[2 * t], a1 = hist[2 * t + 1];
    ssum[t] = a0 + a1;
    __syncthreads();
    for (int off = 1; off < 256; off <<= 1) {
        const int add = (t >= off) ? ssum[t - off] : 0;
        __syncthreads();
        ssum[t] += add;
        __syncthreads();
    }
    const int eb = ssum[t] - (a0 + a1);
    lofs[2 * t]     = eb;
    lofs[2 * t + 1] = eb + a0;
    __syncthreads();
    // global CSR starts for this bucket (coalesced)
    const int seg0 = b * SEGB;
    const int nseg = min(SEGB, M_SEG - seg0);
    for (int sl = t; sl < nseg; sl += 256) ofs[seg0 + sl] = s + lofs[sl];
    __syncthreads();
    // scatter within bucket; lofs doubles as running cursor
    for (int j = s + t; j < e; j += 256) {
        const int2 p = epA[j];
        const int sl = ((unsigned)p.x) >> 16;
        const int col = p.x & 0xFFFF;
        const int seg = seg0 + sl;
        const int g = seg / N_NODES;
        const int pos = atomicAdd(&lofs[sl], 1);
        epB[s + pos] = make_int2((col << 9) | (g << 7), p.y);
    }
}

// ---------------------------------------------------------------------------
// Quad-segment CSR SpMM: one wave = 4 segments (16 lanes x 4 features each;
// N_NODES % 4 == 0 so a quad never straddles a group). Branch-free inner
// loop: clamped always-valid loads, weight zeroed via cndmask for exhausted
// quarters. Each load/VALU instruction retires 4 edges.
// ---------------------------------------------------------------------------
__global__ __launch_bounds__(256) void spmm_csr_kernel(
    const unsigned short* __restrict__ xb, const int2* __restrict__ ep,
    const int* __restrict__ ofs, unsigned short* __restrict__ tmpb)
{
    const int w   = (blockIdx.x * 256 + threadIdx.x) >> 6;   // wave id (quad)
    const int tl  = threadIdx.x & 63;
    const int q   = tl >> 4;            // quarter 0..3
    const int ls  = tl & 15;            // lane-in-quarter
    const int seg = w * 4 + q;
    const int g   = seg / N_NODES;
    const int row = seg - g * N_NODES;

    const char* __restrict__ xbb = (const char*)xb + ls * 8;

    int j       = ofs[seg];
    const int e = ofs[seg + 1];
    const int emax = (e > 0) ? (e - 1) : 0;   // always-valid clamp index

    float a0 = 0.f, a1 = 0.f, a2 = 0.f, a3 = 0.f;
    while (__ballot(j < e)) {
        #pragma unroll
        for (int u = 0; u < 4; ++u) {
            const int jc = min(j + u, emax);
            const int2 p = ep[jc];
            const uint2 r = *(const uint2*)(xbb + p.x);
            const float v = (j + u < e) ? __int_as_float(p.y) : 0.f;
            a0 = fmaf(v, __uint_as_float(r.x << 16), a0);
            a1 = fmaf(v, __uint_as_float(r.x & 0xFFFF0000u), a1);
            a2 = fmaf(v, __uint_as_float(r.y << 16), a2);
            a3 = fmaf(v, __uint_as_float(r.y & 0xFFFF0000u), a3);
        }
        j += 4;
    }
    const unsigned lo = (unsigned)f2bf(a0) | ((unsigned)f2bf(a1) << 16);
    const unsigned hi = (unsigned)f2bf(a2) | ((unsigned)f2bf(a3) << 16);
    *(uint2*)((char*)tmpb + (size_t)row * 512 + g * 128 + ls * 8) =
        make_uint2(lo, hi);
}

// ---------------------------------------------------------------------------
// MFMA GEMM: C[M,256] = tmp_bf @ W + bias.  A: [M_PAD,256] bf16 row-major,
// Bt: [256,256] bf16 n-major/k-contiguous. 128x128 tile, BK=32, 4 waves.
// ---------------------------------------------------------------------------
#define TBK 32
#define LDP 40   // padded LDS row (ushorts): 80B stride spreads all 32 banks

__global__ __launch_bounds__(256) void gemm_mfma_kernel(
    const unsigned short* __restrict__ A, const unsigned short* __restrict__ Bt,
    const float* __restrict__ bias, float* __restrict__ C)
{
    __shared__ unsigned short As[128][LDP];   // 10 KB
    __shared__ unsigned short Bs[128][LDP];   // 10 KB

    const int tid = threadIdx.x;
    const int wid = tid >> 6, lane = tid & 63;
    const int wm = (wid & 1) * 64, wn = (wid >> 1) * 64;
    const int lm = lane & 15, lq = lane >> 4;
    const int row0 = blockIdx.x * 128, col0 = blockIdx.y * 128;

    f32x4 acc[4][4] = {};

    for (int k0 = 0; k0 < D_FEAT; k0 += TBK) {
        // A tile: 128 rows x 32 k; 64B/row = 4 x 16B chunks; 2 chunks/thread
        #pragma unroll
        for (int l = 0; l < 2; ++l) {
            const int chunk = tid + l * 256;     // 0..511
            const int r = chunk >> 2;
            const int c = (chunk & 3) * 8;
            uint4 v = make_uint4(0u, 0u, 0u, 0u);
            const int gr = row0 + r;
            if (gr < N_NODES)
                v = *(const uint4*)&A[(long long)gr * D_FEAT + k0 + c];
            *(uint4*)&As[r][c] = v;
        }
        #pragma unroll
        for (int l = 0; l < 2; ++l) {
            const int chunk = tid + l * 256;
            const int r = chunk >> 2;
            const int c = (chunk & 3) * 8;
            *(uint4*)&Bs[r][c] =
                *(const uint4*)&Bt[(long long)(col0 + r) * D_FEAT + k0 + c];
        }
        __syncthreads();

        bf16x8 af[4], bfr[4];
        #pragma unroll
        for (int mi = 0; mi < 4; ++mi)
            af[mi] = *(const bf16x8*)&As[wm + mi * 16 + lm][lq * 8];
        #pragma unroll
        for (int ni = 0; ni < 4; ++ni)
            bfr[ni] = *(const bf16x8*)&Bs[wn + ni * 16 + lm][lq * 8];
        #pragma unroll
        for (int mi = 0; mi < 4; ++mi)
            #pragma unroll
            for (int ni = 0; ni < 4; ++ni)
                acc[mi][ni] = __builtin_amdgcn_mfma_f32_16x16x32_bf16(
                    af[mi], bfr[ni], acc[mi][ni], 0, 0, 0);
        __syncthreads();
    }

    // D layout: col = lane&15, row = (lane>>4)*4 + reg
    #pragma unroll
    for (int mi = 0; mi < 4; ++mi) {
        #pragma unroll
        for (int ni = 0; ni < 4; ++ni) {
            const int n = col0 + wn + ni * 16 + lm;
            const float b = bias[n];
            #pragma unroll
            for (int r = 0; r < 4; ++r) {
                const int m = row0 + wm + mi * 16 + lq * 4 + r;
                if (m < N_NODES)
                    C[(long long)m * D_FEAT + n] = acc[mi][ni][r] + b;
            }
        }
    }
}

// ---------------------------------------------------------------------------
// Fallback path (atomic f32 spmm + f32 GEMM) — only if ws too small.
// ---------------------------------------------------------------------------
__global__ __launch_bounds__(256) void spmm_scatter_kernel(
    const float* __restrict__ x, const int* __restrict__ edge_row,
    const int* __restrict__ edge_col, const float* __restrict__ edge_val,
    float* __restrict__ tmp)
{
    const long long gtid = (long long)blockIdx.x * blockDim.x + threadIdx.x;
    const int wave = (int)(gtid >> 6);
    const int lane = threadIdx.x & 63;
    if (wave >= TOT_E) return;
    const int g = wave / E_EDGES;
    const int row = edge_row[wave];
    const int col = edge_col[wave];
    const float val = edge_val[wave];
    atomicAdd(&tmp[(long long)row * D_FEAT + g * DG + lane],
              val * x[(long long)col * D_FEAT + g * DG + lane]);
}

__global__ __launch_bounds__(256) void gemm_bias_kernel(
    const float* __restrict__ A, const float* __restrict__ W,
    const float* __restrict__ bias, float* __restrict__ C)
{
    __shared__ float Asf[64][68];
    __shared__ float Wsf[64][68];
    const int tid = threadIdx.x;
    const int tx = tid & 15, ty = tid >> 4;
    const int row0 = blockIdx.x * 64, col0 = blockIdx.y * 64;
    float acc[4][4] = {};
    for (int k0 = 0; k0 < D_FEAT; k0 += 64) {
        #pragma unroll
        for (int l = 0; l < 4; ++l) {
            const int linear = tid + l * 256;
            const int ar = linear >> 4, ac = (linear & 15) << 2;
            float4 v = make_float4(0.f, 0.f, 0.f, 0.f);
            const int gr = row0 + ar;
            if (gr < N_NODES) v = *(const float4*)&A[(long long)gr * D_FEAT + k0 + ac];
            Asf[ac + 0][ar] = v.x; Asf[ac + 1][ar] = v.y;
            Asf[ac + 2][ar] = v.z; Asf[ac + 3][ar] = v.w;
        }
        #pragma unroll
        for (int l = 0; l < 4; ++l) {
            const int linear = tid + l * 256;
            const int wr = linear >> 4, wc = (linear & 15) << 2;
            *(float4*)&Wsf[wr][wc] =
                *(const float4*)&W[(long long)(k0 + wr) * D_FEAT + col0 + wc];
        }
        __syncthreads();
        #pragma unroll
        for (int k = 0; k < 64; ++k) {
            const float4 a4 = *(const float4*)&Asf[k][ty * 4];
            const float4 b4 = *(const float4*)&Wsf[k][tx * 4];
            const float a[4] = {a4.x, a4.y, a4.z, a4.w};
            const float b[4] = {b4.x, b4.y, b4.z, b4.w};
            #pragma unroll
            for (int i = 0; i < 4; ++i)
                #pragma unroll
                for (int j = 0; j < 4; ++j) acc[i][j] += a[i] * b[j];
        }
        __syncthreads();
    }
    const float4 b4 = *(const float4*)&bias[col0 + tx * 4];
    #pragma unroll
    for (int i = 0; i < 4; ++i) {
        const int gr = row0 + ty * 4 + i;
        if (gr >= N_NODES) continue;
        float4 v;
        v.x = acc[i][0] + b4.x; v.y = acc[i][1] + b4.y;
        v.z = acc[i][2] + b4.z; v.w = acc[i][3] + b4.w;
        *(float4*)&C[(long long)gr * D_FEAT + col0 + tx * 4] = v;
    }
}

// ---------------------------------------------------------------------------
extern "C" void kernel_launch(void* const* d_in, const int* in_sizes, int n_in,
                              void* d_out, int out_size, void* d_ws, size_t ws_size,
                              hipStream_t stream)
{
    const float* x        = (const float*)d_in[0];
    const int*   edge_row = (const int*)d_in[1];
    const int*   edge_col = (const int*)d_in[2];
    const float* edge_val = (const float*)d_in[3];
    const float* weight   = (const float*)d_in[4];
    const float* bias     = (const float*)d_in[5];
    float* out = (float*)d_out;

    char* p = (char*)d_ws;
    auto alloc = [&](size_t bytes) {
        char* r = p;
        p += (bytes + 255) & ~(size_t)255;
        return r;
    };
    unsigned short* xb   = (unsigned short*)alloc((size_t)N_NODES * D_FEAT * 2); // 25.6 MB
    unsigned short* tmpb = (unsigned short*)alloc((size_t)M_PAD * D_FEAT * 2);   // 25.6 MB
    unsigned short* Wt   = (unsigned short*)alloc((size_t)D_FEAT * D_FEAT * 2);  // 128 KB
    int2* epB = (int2*)alloc((size_t)TOT_E * sizeof(int2));                      // 25.6 MB
    int* cntA = (int*)alloc((size_t)NB1 * sizeof(int));
    int* ofsA = (int*)alloc((size_t)(NB1 + 1) * sizeof(int));
    int* curA = (int*)alloc((size_t)NB1 * sizeof(int));
    int* ofs  = (int*)alloc((size_t)(M_SEG + 1) * sizeof(int));                  // 800 KB
    const size_t needed = (size_t)(p - (char*)d_ws);

    // epA aliases tmpb: TOT_E*8 = 25,600,000 B <= M_PAD*256*2 = 25,624,576 B.
    // epA is dead before spmm_csr writes tmpb (stream-ordered).
    int2* epA = (int2*)tmpb;

    if (ws_size >= needed) {
        hipMemsetAsync(cntA, 0, (size_t)NB1 * sizeof(int), stream);
        convert_x_kernel<<<(N_NODES * D_FEAT / 8 + 255) / 256, 256, 0, stream>>>(x, xb);
        convert_w_kernel<<<D_FEAT, D_FEAT, 0, stream>>>(weight, Wt);
        countA_kernel<<<CA_BLOCKS, 256, 0, stream>>>(edge_row, cntA);
        scanA_kernel<<<1, 256, 0, stream>>>(cntA, ofsA, curA, ofs);
        scatterA_kernel<<<CA_BLOCKS, 256, 0, stream>>>(
            edge_row, edge_col, edge_val, curA, epA);
        sortB_kernel<<<NB1, 256, 0, stream>>>(epA, ofsA, epB, ofs);
        spmm_csr_kernel<<<(M_SEG / 4) * 64 / 256, 256, 0, stream>>>(xb, epB, ofs, tmpb);
        dim3 grid(M_PAD / 128, D_FEAT / 128);
        gemm_mfma_kernel<<<grid, 256, 0, stream>>>(tmpb, Wt, bias, out);
    } else {
        float* tmp = (float*)d_ws;
        hipMemsetAsync(tmp, 0, (size_t)N_NODES * D_FEAT * sizeof(float), stream);
        const long long total_threads = (long long)TOT_E * 64;
        spmm_scatter_kernel<<<(int)((total_threads + 255) / 256), 256, 0, stream>>>(
            x, edge_row, edge_col, edge_val, tmp);
        dim3 grid2((N_NODES + 63) / 64, D_FEAT / 64);
        gemm_bias_kernel<<<grid2, 256, 0, stream>>>(tmp, weight, bias, out);
    }
}

// Round 6
// 325.539 us; speedup vs baseline: 4.8715x; 1.1045x over previous
//
#include <hip/hip_runtime.h>
#include <hip/hip_bf16.h>

#define N_NODES 50000
#define D_FEAT  256
#define G_GROUPS 4
#define E_EDGES 800000
#define DG      64
#define M_SEG   (G_GROUPS * N_NODES)        // 200000 segments
#define TOT_E   (G_GROUPS * E_EDGES)        // 3200000 edges
#define M_PAD   50048                       // 391 * 128

// two-level counting sort geometry
#define SEGB      512                        // segments per coarse bucket (2^9)
#define NB1       391                        // ceil(M_SEG / SEGB)
#define CA_BLOCKS 400
#define CHA       8000                       // 400 * 8000 == TOT_E exact
#define PADMAX    512                        // max per-bucket pad entries (1/seg)

typedef short bf16x8 __attribute__((ext_vector_type(8)));   // 8 bf16 (4 VGPRs)
typedef float f32x4  __attribute__((ext_vector_type(4)));

__device__ __forceinline__ unsigned short f2bf(float f) {
    unsigned int u = __float_as_uint(f);
    u += 0x7FFF + ((u >> 16) & 1);          // RNE
    return (unsigned short)(u >> 16);
}
__device__ __forceinline__ float bf2f(unsigned short h) {
    return __uint_as_float((unsigned int)h << 16);
}

// ---------------------------------------------------------------------------
// x (f32 [N,256]) -> x_bf (bf16). 8 elems / thread.
// ---------------------------------------------------------------------------
__global__ __launch_bounds__(256) void convert_x_kernel(
    const float* __restrict__ x, unsigned short* __restrict__ xb)
{
    const long long base = ((long long)blockIdx.x * 256 + threadIdx.x) * 8;
    if (base >= (long long)N_NODES * D_FEAT) return;
    const float4 v0 = *(const float4*)&x[base];
    const float4 v1 = *(const float4*)&x[base + 4];
    unsigned short r[8];
    r[0] = f2bf(v0.x); r[1] = f2bf(v0.y); r[2] = f2bf(v0.z); r[3] = f2bf(v0.w);
    r[4] = f2bf(v1.x); r[5] = f2bf(v1.y); r[6] = f2bf(v1.z); r[7] = f2bf(v1.w);
    *(uint4*)&xb[base] = *(const uint4*)r;
}

// W [K=256, N=256] f32 -> Wt [n][k] bf16 (transposed, k-contiguous)
__global__ __launch_bounds__(256) void convert_w_kernel(
    const float* __restrict__ W, unsigned short* __restrict__ Wt)
{
    const int n = blockIdx.x;       // 256 blocks
    const int k = threadIdx.x;      // 256 threads
    Wt[n * D_FEAT + k] = f2bf(W[k * D_FEAT + n]);
}

// ---------------------------------------------------------------------------
// Pass A1: global per-coarse-bucket counts (LDS-staged histogram).
// ---------------------------------------------------------------------------
__global__ __launch_bounds__(256) void countA_kernel(
    const int* __restrict__ edge_row, int* __restrict__ cntA)
{
    __shared__ int h[NB1];
    const int t = threadIdx.x;
    for (int i = t; i < NB1; i += 256) h[i] = 0;
    __syncthreads();
    const int start = blockIdx.x * CHA;
    const int end   = start + CHA;
    for (int i = start + t; i < end; i += 256) {
        const int g = i / E_EDGES;
        const int seg = g * N_NODES + edge_row[i];
        atomicAdd(&h[seg >> 9], 1);
    }
    __syncthreads();
    for (int i = t; i < NB1; i += 256)
        if (h[i]) atomicAdd(&cntA[i], h[i]);
}

// ---------------------------------------------------------------------------
// Pass A2: single-block exclusive scan of the 391 bucket counts.
// Writes ofsA[] (raw bucket region starts, 392 entries) and curA[].
// ---------------------------------------------------------------------------
__global__ __launch_bounds__(256) void scanA_kernel(
    const int* __restrict__ cntA, int* __restrict__ ofsA, int* __restrict__ curA)
{
    __shared__ int ssum[256];
    const int t = threadIdx.x;
    const int i0 = 2 * t, i1 = 2 * t + 1;
    const int v0 = (i0 < NB1) ? cntA[i0] : 0;
    const int v1 = (i1 < NB1) ? cntA[i1] : 0;
    ssum[t] = v0 + v1;
    __syncthreads();
    for (int off = 1; off < 256; off <<= 1) {
        const int add = (t >= off) ? ssum[t - off] : 0;
        __syncthreads();
        ssum[t] += add;
        __syncthreads();
    }
    const int eb = ssum[t] - (v0 + v1);       // exclusive base of pair
    if (i0 < NB1) { ofsA[i0] = eb;      curA[i0] = eb; }
    if (i1 < NB1) { ofsA[i1] = eb + v0; curA[i1] = eb + v0; }
    if (t == 255) ofsA[NB1] = ssum[255];      // == TOT_E
}

// ---------------------------------------------------------------------------
// Pass A3: coarse scatter. Each block histograms its chunk, reserves one
// contiguous region per bucket with a single global atomic, then fills its
// own (private, L2-resident) reserved chunks -> full-line writebacks.
// Payload packs {col (16b) | seg_local (9b) << 16, val_bits}.
// ---------------------------------------------------------------------------
__global__ __launch_bounds__(256) void scatterA_kernel(
    const int* __restrict__ edge_row, const int* __restrict__ edge_col,
    const float* __restrict__ edge_val, int* __restrict__ curA,
    int2* __restrict__ epA)
{
    __shared__ int hist[NB1];
    __shared__ int gcur[NB1];
    const int t = threadIdx.x;
    for (int i = t; i < NB1; i += 256) hist[i] = 0;
    __syncthreads();
    const int start = blockIdx.x * CHA;
    const int end   = start + CHA;
    for (int i = start + t; i < end; i += 256) {
        const int g = i / E_EDGES;
        const int seg = g * N_NODES + edge_row[i];
        atomicAdd(&hist[seg >> 9], 1);
    }
    __syncthreads();
    for (int i = t; i < NB1; i += 256)
        gcur[i] = hist[i] ? atomicAdd(&curA[i], hist[i]) : 0;
    __syncthreads();
    for (int i = start + t; i < end; i += 256) {
        const int g = i / E_EDGES;
        const int seg = g * N_NODES + edge_row[i];
        const int bk = seg >> 9;
        const int sl = seg & (SEGB - 1);
        const int pos = atomicAdd(&gcur[bk], 1);
        epA[pos] = make_int2(edge_col[i] | (sl << 16), __float_as_int(edge_val[i]));
    }
}

// ---------------------------------------------------------------------------
// Pass B: fine sort within each coarse bucket. One block per bucket.
// epB layout: bucket base = ofsA[b] + b*PADMAX; every segment padded to an
// EVEN edge count with {0,0} (val=0 -> exact). ofs[seg] packs
// start(24b) | padded_cnt(8b). epB.x is the PRE-SCALED byte offset into xb:
// col*512 + g*128.
// ---------------------------------------------------------------------------
__global__ __launch_bounds__(256) void sortB_kernel(
    const int2* __restrict__ epA, const int* __restrict__ ofsA,
    int2* __restrict__ epB, unsigned* __restrict__ ofs)
{
    __shared__ int hist[SEGB];
    __shared__ int lofs[SEGB];
    __shared__ int cur[SEGB];
    __shared__ int ssum[256];
    const int b = blockIdx.x;
    const int t = threadIdx.x;
    const int s = ofsA[b], e = ofsA[b + 1];
    const int base = s + b * PADMAX;
    hist[t] = 0; hist[t + 256] = 0;
    __syncthreads();
    for (int j = s + t; j < e; j += 256)
        atomicAdd(&hist[((unsigned)epA[j].x) >> 16], 1);
    __syncthreads();
    // pair-wise exclusive scan of PADDED (even) counts
    const int c0 = hist[2 * t], c1 = hist[2 * t + 1];
    const int p0 = c0 + (c0 & 1), p1 = c1 + (c1 & 1);
    ssum[t] = p0 + p1;
    __syncthreads();
    for (int off = 1; off < 256; off <<= 1) {
        const int add = (t >= off) ? ssum[t - off] : 0;
        __syncthreads();
        ssum[t] += add;
        __syncthreads();
    }
    const int eb = ssum[t] - (p0 + p1);
    lofs[2 * t]     = eb;      cur[2 * t]     = eb;
    lofs[2 * t + 1] = eb + p0; cur[2 * t + 1] = eb + p0;
    __syncthreads();
    // packed CSR words (coalesced)
    const int seg0 = b * SEGB;
    const int nseg = min(SEGB, M_SEG - seg0);
    for (int sl = t; sl < nseg; sl += 256) {
        const int pc = hist[sl] + (hist[sl] & 1);
        ofs[seg0 + sl] = (unsigned)(base + lofs[sl]) | ((unsigned)pc << 24);
    }
    // scatter within bucket (cur = running cursors)
    for (int j = s + t; j < e; j += 256) {
        const int2 p = epA[j];
        const int sl = ((unsigned)p.x) >> 16;
        const int col = p.x & 0xFFFF;
        const int seg = seg0 + sl;
        const int g = seg / N_NODES;
        const int pos = atomicAdd(&cur[sl], 1);
        epB[base + pos] = make_int2((col << 9) | (g << 7), p.y);
    }
    // pad entries (slots disjoint from scatter writes -> no sync needed)
    for (int sl = t; sl < nseg; sl += 256)
        if (hist[sl] & 1)
            epB[base + lofs[sl] + hist[sl]] = make_int2(0, 0);
}

// ---------------------------------------------------------------------------
// Octo-segment CSR SpMM: one wave = 8 segments (8 lanes x 8 features each;
// N_NODES % 8 == 0 so an octant never straddles a group). Pair-wise int4 ep
// loads (2 edges / load, segments even-padded), uint4 16B gathers. Branch-
// free: clamped always-valid ep loads; BOTH the gather address and the
// weight are predicated (address -> 0 for exhausted/empty lanes, so a
// garbage ep word from an uninitialized gap can never form a wild gather).
// ---------------------------------------------------------------------------
__global__ __launch_bounds__(256) void spmm_csr_kernel(
    const unsigned short* __restrict__ xb, const int2* __restrict__ ep,
    const unsigned* __restrict__ ofs, unsigned short* __restrict__ tmpb)
{
    const int w   = (blockIdx.x * 256 + threadIdx.x) >> 6;   // wave id
    const int tl  = threadIdx.x & 63;
    const int o   = tl >> 3;            // octant 0..7
    const int ls  = tl & 7;             // lane-in-octant
    const int seg = w * 8 + o;
    const int g   = seg / N_NODES;
    const int row = seg - g * N_NODES;

    const char* __restrict__ xbb = (const char*)xb + ls * 16;

    const unsigned po = ofs[seg];
    int j       = (int)(po & 0xFFFFFFu);
    const int e = j + (int)(po >> 24);           // even count (padded)
    const int emax2 = (e - 2 < j) ? j : (e - 2); // even, always-valid pair base

    float a0 = 0.f, a1 = 0.f, a2 = 0.f, a3 = 0.f;
    float a4 = 0.f, a5 = 0.f, a6 = 0.f, a7 = 0.f;

#define ACC8(v, r)                                          \
    a0 = fmaf(v, __uint_as_float((r).x << 16), a0);         \
    a1 = fmaf(v, __uint_as_float((r).x & 0xFFFF0000u), a1); \
    a2 = fmaf(v, __uint_as_float((r).y << 16), a2);         \
    a3 = fmaf(v, __uint_as_float((r).y & 0xFFFF0000u), a3); \
    a4 = fmaf(v, __uint_as_float((r).z << 16), a4);         \
    a5 = fmaf(v, __uint_as_float((r).z & 0xFFFF0000u), a5); \
    a6 = fmaf(v, __uint_as_float((r).w << 16), a6);         \
    a7 = fmaf(v, __uint_as_float((r).w & 0xFFFF0000u), a7);

    while (__ballot(j < e)) {
        const int jc0 = min(j, emax2);
        const int jc1 = min(j + 2, emax2);
        const int4 q0 = *(const int4*)&ep[jc0];   // edges jc0, jc0+1
        const int4 q1 = *(const int4*)&ep[jc1];   // edges jc1, jc1+1
        const bool cA = j < e;            // covers j and j+1 (e-j even)
        const bool cB = (j + 2) < e;      // covers j+2 and j+3
        // predicated gather addresses: garbage ep data can never fault
        const int o0 = cA ? q0.x : 0;
        const int o1 = cA ? q0.z : 0;
        const int o2 = cB ? q1.x : 0;
        const int o3 = cB ? q1.z : 0;
        const uint4 r0 = *(const uint4*)(xbb + o0);
        const uint4 r1 = *(const uint4*)(xbb + o1);
        const uint4 r2 = *(const uint4*)(xbb + o2);
        const uint4 r3 = *(const uint4*)(xbb + o3);
        const float v0 = cA ? __int_as_float(q0.y) : 0.f;
        const float v1 = cA ? __int_as_float(q0.w) : 0.f;
        const float v2 = cB ? __int_as_float(q1.y) : 0.f;
        const float v3 = cB ? __int_as_float(q1.w) : 0.f;
        ACC8(v0, r0)
        ACC8(v1, r1)
        ACC8(v2, r2)
        ACC8(v3, r3)
        j += 4;
    }
#undef ACC8

    const unsigned o0w = (unsigned)f2bf(a0) | ((unsigned)f2bf(a1) << 16);
    const unsigned o1w = (unsigned)f2bf(a2) | ((unsigned)f2bf(a3) << 16);
    const unsigned o2w = (unsigned)f2bf(a4) | ((unsigned)f2bf(a5) << 16);
    const unsigned o3w = (unsigned)f2bf(a6) | ((unsigned)f2bf(a7) << 16);
    *(uint4*)((char*)tmpb + (size_t)row * 512 + g * 128 + ls * 16) =
        make_uint4(o0w, o1w, o2w, o3w);
}

// ---------------------------------------------------------------------------
// MFMA GEMM: C[M,256] = tmp_bf @ W + bias.  A: [M_PAD,256] bf16 row-major,
// Bt: [256,256] bf16 n-major/k-contiguous. 128x128 tile, BK=32, 4 waves.
// ---------------------------------------------------------------------------
#define TBK 32
#define LDP 40   // padded LDS row (ushorts): 80B stride spreads all 32 banks

__global__ __launch_bounds__(256) void gemm_mfma_kernel(
    const unsigned short* __restrict__ A, const unsigned short* __restrict__ Bt,
    const float* __restrict__ bias, float* __restrict__ C)
{
    __shared__ unsigned short As[128][LDP];   // 10 KB
    __shared__ unsigned short Bs[128][LDP];   // 10 KB

    const int tid = threadIdx.x;
    const int wid = tid >> 6, lane = tid & 63;
    const int wm = (wid & 1) * 64, wn = (wid >> 1) * 64;
    const int lm = lane & 15, lq = lane >> 4;
    const int row0 = blockIdx.x * 128, col0 = blockIdx.y * 128;

    f32x4 acc[4][4] = {};

    for (int k0 = 0; k0 < D_FEAT; k0 += TBK) {
        // A tile: 128 rows x 32 k; 64B/row = 4 x 16B chunks; 2 chunks/thread
        #pragma unroll
        for (int l = 0; l < 2; ++l) {
            const int chunk = tid + l * 256;     // 0..511
            const int r = chunk >> 2;
            const int c = (chunk & 3) * 8;
            uint4 v = make_uint4(0u, 0u, 0u, 0u);
            const int gr = row0 + r;
            if (gr < N_NODES)
                v = *(const uint4*)&A[(long long)gr * D_FEAT + k0 + c];
            *(uint4*)&As[r][c] = v;
        }
        #pragma unroll
        for (int l = 0; l < 2; ++l) {
            const int chunk = tid + l * 256;
            const int r = chunk >> 2;
            const int c = (chunk & 3) * 8;
            *(uint4*)&Bs[r][c] =
                *(const uint4*)&Bt[(long long)(col0 + r) * D_FEAT + k0 + c];
        }
        __syncthreads();

        bf16x8 af[4], bfr[4];
        #pragma unroll
        for (int mi = 0; mi < 4; ++mi)
            af[mi] = *(const bf16x8*)&As[wm + mi * 16 + lm][lq * 8];
        #pragma unroll
        for (int ni = 0; ni < 4; ++ni)
            bfr[ni] = *(const bf16x8*)&Bs[wn + ni * 16 + lm][lq * 8];
        #pragma unroll
        for (int mi = 0; mi < 4; ++mi)
            #pragma unroll
            for (int ni = 0; ni < 4; ++ni)
                acc[mi][ni] = __builtin_amdgcn_mfma_f32_16x16x32_bf16(
                    af[mi], bfr[ni], acc[mi][ni], 0, 0, 0);
        __syncthreads();
    }

    // D layout: col = lane&15, row = (lane>>4)*4 + reg
    #pragma unroll
    for (int mi = 0; mi < 4; ++mi) {
        #pragma unroll
        for (int ni = 0; ni < 4; ++ni) {
            const int n = col0 + wn + ni * 16 + lm;
            const float b = bias[n];
            #pragma unroll
            for (int r = 0; r < 4; ++r) {
                const int m = row0 + wm + mi * 16 + lq * 4 + r;
                if (m < N_NODES)
                    C[(long long)m * D_FEAT + n] = acc[mi][ni][r] + b;
            }
        }
    }
}

// ---------------------------------------------------------------------------
// Fallback path (atomic f32 spmm + f32 GEMM) — only if ws too small.
// ---------------------------------------------------------------------------
__global__ __launch_bounds__(256) void spmm_scatter_kernel(
    const float* __restrict__ x, const int* __restrict__ edge_row,
    const int* __restrict__ edge_col, const float* __restrict__ edge_val,
    float* __restrict__ tmp)
{
    const long long gtid = (long long)blockIdx.x * blockDim.x + threadIdx.x;
    const int wave = (int)(gtid >> 6);
    const int lane = threadIdx.x & 63;
    if (wave >= TOT_E) return;
    const int g = wave / E_EDGES;
    const int row = edge_row[wave];
    const int col = edge_col[wave];
    const float val = edge_val[wave];
    atomicAdd(&tmp[(long long)row * D_FEAT + g * DG + lane],
              val * x[(long long)col * D_FEAT + g * DG + lane]);
}

__global__ __launch_bounds__(256) void gemm_bias_kernel(
    const float* __restrict__ A, const float* __restrict__ W,
    const float* __restrict__ bias, float* __restrict__ C)
{
    __shared__ float Asf[64][68];
    __shared__ float Wsf[64][68];
    const int tid = threadIdx.x;
    const int tx = tid & 15, ty = tid >> 4;
    const int row0 = blockIdx.x * 64, col0 = blockIdx.y * 64;
    float acc[4][4] = {};
    for (int k0 = 0; k0 < D_FEAT; k0 += 64) {
        #pragma unroll
        for (int l = 0; l < 4; ++l) {
            const int linear = tid + l * 256;
            const int ar = linear >> 4, ac = (linear & 15) << 2;
            float4 v = make_float4(0.f, 0.f, 0.f, 0.f);
            const int gr = row0 + ar;
            if (gr < N_NODES) v = *(const float4*)&A[(long long)gr * D_FEAT + k0 + ac];
            Asf[ac + 0][ar] = v.x; Asf[ac + 1][ar] = v.y;
            Asf[ac + 2][ar] = v.z; Asf[ac + 3][ar] = v.w;
        }
        #pragma unroll
        for (int l = 0; l < 4; ++l) {
            const int linear = tid + l * 256;
            const int wr = linear >> 4, wc = (linear & 15) << 2;
            *(float4*)&Wsf[wr][wc] =
                *(const float4*)&W[(long long)(k0 + wr) * D_FEAT + col0 + wc];
        }
        __syncthreads();
        #pragma unroll
        for (int k = 0; k < 64; ++k) {
            const float4 a4 = *(const float4*)&Asf[k][ty * 4];
            const float4 b4 = *(const float4*)&Wsf[k][tx * 4];
            const float a[4] = {a4.x, a4.y, a4.z, a4.w};
            const float b[4] = {b4.x, b4.y, b4.z, b4.w};
            #pragma unroll
            for (int i = 0; i < 4; ++i)
                #pragma unroll
                for (int j = 0; j < 4; ++j) acc[i][j] += a[i] * b[j];
        }
        __syncthreads();
    }
    const float4 b4 = *(const float4*)&bias[col0 + tx * 4];
    #pragma unroll
    for (int i = 0; i < 4; ++i) {
        const int gr = row0 + ty * 4 + i;
        if (gr >= N_NODES) continue;
        float4 v;
        v.x = acc[i][0] + b4.x; v.y = acc[i][1] + b4.y;
        v.z = acc[i][2] + b4.z; v.w = acc[i][3] + b4.w;
        *(float4*)&C[(long long)gr * D_FEAT + col0 + tx * 4] = v;
    }
}

// ---------------------------------------------------------------------------
extern "C" void kernel_launch(void* const* d_in, const int* in_sizes, int n_in,
                              void* d_out, int out_size, void* d_ws, size_t ws_size,
                              hipStream_t stream)
{
    const float* x        = (const float*)d_in[0];
    const int*   edge_row = (const int*)d_in[1];
    const int*   edge_col = (const int*)d_in[2];
    const float* edge_val = (const float*)d_in[3];
    const float* weight   = (const float*)d_in[4];
    const float* bias     = (const float*)d_in[5];
    float* out = (float*)d_out;

    char* p = (char*)d_ws;
    auto alloc = [&](size_t bytes) {
        char* r = p;
        p += (bytes + 255) & ~(size_t)255;
        return r;
    };
    unsigned short* xb   = (unsigned short*)alloc((size_t)N_NODES * D_FEAT * 2); // 25.6 MB
    unsigned short* tmpb = (unsigned short*)alloc((size_t)M_PAD * D_FEAT * 2);   // 25.6 MB
    unsigned short* Wt   = (unsigned short*)alloc((size_t)D_FEAT * D_FEAT * 2);  // 128 KB
    int2* epB = (int2*)alloc(((size_t)TOT_E + (size_t)NB1 * PADMAX + 8)
                             * sizeof(int2));                                    // 27.2 MB
    int* cntA = (int*)alloc((size_t)NB1 * sizeof(int));
    int* ofsA = (int*)alloc((size_t)(NB1 + 1) * sizeof(int));
    int* curA = (int*)alloc((size_t)NB1 * sizeof(int));
    unsigned* ofs = (unsigned*)alloc((size_t)M_SEG * sizeof(unsigned));          // 800 KB
    const size_t needed = (size_t)(p - (char*)d_ws);

    // epA aliases tmpb: TOT_E*8 = 25,600,000 B <= M_PAD*256*2 = 25,624,576 B.
    // epA is dead before spmm_csr writes tmpb (stream-ordered).
    int2* epA = (int2*)tmpb;

    if (ws_size >= needed) {
        hipMemsetAsync(cntA, 0, (size_t)NB1 * sizeof(int), stream);
        convert_x_kernel<<<(N_NODES * D_FEAT / 8 + 255) / 256, 256, 0, stream>>>(x, xb);
        convert_w_kernel<<<D_FEAT, D_FEAT, 0, stream>>>(weight, Wt);
        countA_kernel<<<CA_BLOCKS, 256, 0, stream>>>(edge_row, cntA);
        scanA_kernel<<<1, 256, 0, stream>>>(cntA, ofsA, curA);
        scatterA_kernel<<<CA_BLOCKS, 256, 0, stream>>>(
            edge_row, edge_col, edge_val, curA, epA);
        sortB_kernel<<<NB1, 256, 0, stream>>>(epA, ofsA, epB, ofs);
        spmm_csr_kernel<<<(M_SEG / 8) * 64 / 256, 256, 0, stream>>>(xb, epB, ofs, tmpb);
        dim3 grid(M_PAD / 128, D_FEAT / 128);
        gemm_mfma_kernel<<<grid, 256, 0, stream>>>(tmpb, Wt, bias, out);
    } else {
        float* tmp = (float*)d_ws;
        hipMemsetAsync(tmp, 0, (size_t)N_NODES * D_FEAT * sizeof(float), stream);
        const long long total_threads = (long long)TOT_E * 64;
        spmm_scatter_kernel<<<(int)((total_threads + 255) / 256), 256, 0, stream>>>(
            x, edge_row, edge_col, edge_val, tmp);
        dim3 grid2((N_NODES + 63) / 64, D_FEAT / 64);
        gemm_bias_kernel<<<grid2, 256, 0, stream>>>(tmp, weight, bias, out);
    }
}

// Round 7
// 293.271 us; speedup vs baseline: 5.4076x; 1.1100x over previous
//
#include <hip/hip_runtime.h>
#include <hip/hip_bf16.h>

#define N_NODES 50000
#define D_FEAT  256
#define G_GROUPS 4
#define E_EDGES 800000
#define DG      64
#define M_SEG   (G_GROUPS * N_NODES)        // 200000 segments
#define TOT_E   (G_GROUPS * E_EDGES)        // 3200000 edges
#define M_PAD   50048                       // 391 * 128

// two-level counting sort geometry
#define SEGB      512                        // segments per coarse bucket (2^9)
#define NB1       391                        // ceil(M_SEG / SEGB)
#define CA_BLOCKS 400
#define CHA       8000                       // 400 * 8000 == TOT_E exact; CHA | E_EDGES
#define CHG       (CHA / 4)                  // 2000 int4 groups per chunk
#define PADMAX    512                        // max per-bucket pad entries (1/seg)

typedef short bf16x8 __attribute__((ext_vector_type(8)));   // 8 bf16 (4 VGPRs)
typedef float f32x4  __attribute__((ext_vector_type(4)));

__device__ __forceinline__ unsigned short f2bf(float f) {
    unsigned int u = __float_as_uint(f);
    u += 0x7FFF + ((u >> 16) & 1);          // RNE
    return (unsigned short)(u >> 16);
}
__device__ __forceinline__ float bf2f(unsigned short h) {
    return __uint_as_float((unsigned int)h << 16);
}

// ---------------------------------------------------------------------------
// x (f32 [N,256]) -> x_bf (bf16). 8 elems / thread.
// ---------------------------------------------------------------------------
__global__ __launch_bounds__(256) void convert_x_kernel(
    const float* __restrict__ x, unsigned short* __restrict__ xb)
{
    const long long base = ((long long)blockIdx.x * 256 + threadIdx.x) * 8;
    if (base >= (long long)N_NODES * D_FEAT) return;
    const float4 v0 = *(const float4*)&x[base];
    const float4 v1 = *(const float4*)&x[base + 4];
    unsigned short r[8];
    r[0] = f2bf(v0.x); r[1] = f2bf(v0.y); r[2] = f2bf(v0.z); r[3] = f2bf(v0.w);
    r[4] = f2bf(v1.x); r[5] = f2bf(v1.y); r[6] = f2bf(v1.z); r[7] = f2bf(v1.w);
    *(uint4*)&xb[base] = *(const uint4*)r;
}

// W [K=256, N=256] f32 -> Wt [n][k] bf16 (transposed, k-contiguous)
__global__ __launch_bounds__(256) void convert_w_kernel(
    const float* __restrict__ W, unsigned short* __restrict__ Wt)
{
    const int n = blockIdx.x;       // 256 blocks
    const int k = threadIdx.x;      // 256 threads
    Wt[n * D_FEAT + k] = f2bf(W[k * D_FEAT + n]);
}

// ---------------------------------------------------------------------------
// Pass A1: per-coarse-bucket counts. 1024 threads, int4 edge loads.
// Each chunk lies entirely in ONE group (CHA | E_EDGES) -> g is per-block.
// ---------------------------------------------------------------------------
__global__ __launch_bounds__(1024) void countA_kernel(
    const int* __restrict__ edge_row, int* __restrict__ cntA)
{
    __shared__ int h[NB1];
    const int t = threadIdx.x;
    if (t < NB1) h[t] = 0;
    __syncthreads();
    const int start = blockIdx.x * CHA;
    const int segbase = (start / E_EDGES) * N_NODES;
    for (int gi = t; gi < CHG; gi += 1024) {
        const int4 r = *(const int4*)&edge_row[start + gi * 4];
        atomicAdd(&h[(segbase + r.x) >> 9], 1);
        atomicAdd(&h[(segbase + r.y) >> 9], 1);
        atomicAdd(&h[(segbase + r.z) >> 9], 1);
        atomicAdd(&h[(segbase + r.w) >> 9], 1);
    }
    __syncthreads();
    if (t < NB1 && h[t]) atomicAdd(&cntA[t], h[t]);
}

// ---------------------------------------------------------------------------
// Pass A2: single-block exclusive scan of the 391 bucket counts.
// Writes ofsA[] (raw bucket region starts, 392 entries) and curA[].
// ---------------------------------------------------------------------------
__global__ __launch_bounds__(256) void scanA_kernel(
    const int* __restrict__ cntA, int* __restrict__ ofsA, int* __restrict__ curA)
{
    __shared__ int ssum[256];
    const int t = threadIdx.x;
    const int i0 = 2 * t, i1 = 2 * t + 1;
    const int v0 = (i0 < NB1) ? cntA[i0] : 0;
    const int v1 = (i1 < NB1) ? cntA[i1] : 0;
    ssum[t] = v0 + v1;
    __syncthreads();
    for (int off = 1; off < 256; off <<= 1) {
        const int add = (t >= off) ? ssum[t - off] : 0;
        __syncthreads();
        ssum[t] += add;
        __syncthreads();
    }
    const int eb = ssum[t] - (v0 + v1);       // exclusive base of pair
    if (i0 < NB1) { ofsA[i0] = eb;      curA[i0] = eb; }
    if (i1 < NB1) { ofsA[i1] = eb + v0; curA[i1] = eb + v0; }
    if (t == 255) ofsA[NB1] = ssum[255];      // == TOT_E
}

// ---------------------------------------------------------------------------
// Pass A3: coarse scatter. 1024 threads/block; int4 edge loads; rows
// register-cached across phases (each thread owns groups t and t+1024).
// Block histograms its chunk, reserves one contiguous region per bucket
// with a single global atomic, fills its own private (L2-resident)
// reserved chunks -> full-line writebacks.
// Payload packs {col (16b) | seg_local (9b) << 16, val_bits}.
// ---------------------------------------------------------------------------
__global__ __launch_bounds__(1024) void scatterA_kernel(
    const int* __restrict__ edge_row, const int* __restrict__ edge_col,
    const float* __restrict__ edge_val, int* __restrict__ curA,
    int2* __restrict__ epA)
{
    __shared__ int hist[NB1];
    __shared__ int gcur[NB1];
    const int t = threadIdx.x;
    if (t < NB1) hist[t] = 0;
    __syncthreads();
    const int start = blockIdx.x * CHA;
    const int segbase = (start / E_EDGES) * N_NODES;
    const bool hasB = (t + 1024) < CHG;       // t < 976

    // phase 1: load rows once (register cache) + LDS histogram
    const int4 ra = *(const int4*)&edge_row[start + 4 * t];
    int4 rb = make_int4(0, 0, 0, 0);
    if (hasB) rb = *(const int4*)&edge_row[start + 4 * (t + 1024)];
    const int sA0 = segbase + ra.x, sA1 = segbase + ra.y;
    const int sA2 = segbase + ra.z, sA3 = segbase + ra.w;
    atomicAdd(&hist[sA0 >> 9], 1);
    atomicAdd(&hist[sA1 >> 9], 1);
    atomicAdd(&hist[sA2 >> 9], 1);
    atomicAdd(&hist[sA3 >> 9], 1);
    int sB0 = 0, sB1 = 0, sB2 = 0, sB3 = 0;
    if (hasB) {
        sB0 = segbase + rb.x; sB1 = segbase + rb.y;
        sB2 = segbase + rb.z; sB3 = segbase + rb.w;
        atomicAdd(&hist[sB0 >> 9], 1);
        atomicAdd(&hist[sB1 >> 9], 1);
        atomicAdd(&hist[sB2 >> 9], 1);
        atomicAdd(&hist[sB3 >> 9], 1);
    }
    __syncthreads();
    // phase 2: one global reservation per bucket
    if (t < NB1) gcur[t] = hist[t] ? atomicAdd(&curA[t], hist[t]) : 0;
    __syncthreads();
    // phase 3: scatter (col/val re-read as int4; rows from registers)
    {
        const int4 c = *(const int4*)&edge_col[start + 4 * t];
        const int4 v = *(const int4*)&((const int*)edge_val)[start + 4 * t];
        int pos;
        pos = atomicAdd(&gcur[sA0 >> 9], 1);
        epA[pos] = make_int2(c.x | ((sA0 & (SEGB - 1)) << 16), v.x);
        pos = atomicAdd(&gcur[sA1 >> 9], 1);
        epA[pos] = make_int2(c.y | ((sA1 & (SEGB - 1)) << 16), v.y);
        pos = atomicAdd(&gcur[sA2 >> 9], 1);
        epA[pos] = make_int2(c.z | ((sA2 & (SEGB - 1)) << 16), v.z);
        pos = atomicAdd(&gcur[sA3 >> 9], 1);
        epA[pos] = make_int2(c.w | ((sA3 & (SEGB - 1)) << 16), v.w);
    }
    if (hasB) {
        const int4 c = *(const int4*)&edge_col[start + 4 * (t + 1024)];
        const int4 v = *(const int4*)&((const int*)edge_val)[start + 4 * (t + 1024)];
        int pos;
        pos = atomicAdd(&gcur[sB0 >> 9], 1);
        epA[pos] = make_int2(c.x | ((sB0 & (SEGB - 1)) << 16), v.x);
        pos = atomicAdd(&gcur[sB1 >> 9], 1);
        epA[pos] = make_int2(c.y | ((sB1 & (SEGB - 1)) << 16), v.y);
        pos = atomicAdd(&gcur[sB2 >> 9], 1);
        epA[pos] = make_int2(c.z | ((sB2 & (SEGB - 1)) << 16), v.z);
        pos = atomicAdd(&gcur[sB3 >> 9], 1);
        epA[pos] = make_int2(c.w | ((sB3 & (SEGB - 1)) << 16), v.w);
    }
}

// ---------------------------------------------------------------------------
// Pass B: fine sort within each coarse bucket. One 512-thread block per
// bucket. epB layout: bucket base = ofsA[b] + b*PADMAX; every segment
// padded to an EVEN edge count with {0,0} (val=0 -> exact). ofs[seg] packs
// start(24b) | padded_cnt(8b). epB.x is the PRE-SCALED byte offset into xb:
// col*512 + g*128.
// ---------------------------------------------------------------------------
__global__ __launch_bounds__(512) void sortB_kernel(
    const int2* __restrict__ epA, const int* __restrict__ ofsA,
    int2* __restrict__ epB, unsigned* __restrict__ ofs)
{
    __shared__ int hist[SEGB];
    __shared__ int lofs[SEGB];
    __shared__ int cur[SEGB];
    __shared__ int ssum[256];
    const int b = blockIdx.x;
    const int t = threadIdx.x;
    const int s = ofsA[b], e = ofsA[b + 1];
    const int base = s + b * PADMAX;
    hist[t] = 0;
    __syncthreads();
    for (int j = s + t; j < e; j += 512)
        atomicAdd(&hist[((unsigned)epA[j].x) >> 16], 1);
    __syncthreads();
    // pair-wise exclusive scan of PADDED (even) counts (first 256 lanes)
    int p0 = 0, p1 = 0, sum = 0;
    if (t < 256) {
        const int c0 = hist[2 * t], c1 = hist[2 * t + 1];
        p0 = c0 + (c0 & 1); p1 = c1 + (c1 & 1);
        sum = p0 + p1;
        ssum[t] = sum;
    }
    __syncthreads();
    for (int off = 1; off < 256; off <<= 1) {
        int add = 0;
        if (t < 256 && t >= off) add = ssum[t - off];
        __syncthreads();
        if (t < 256) ssum[t] += add;
        __syncthreads();
    }
    if (t < 256) {
        const int eb = ssum[t] - sum;
        lofs[2 * t]     = eb;      cur[2 * t]     = eb;
        lofs[2 * t + 1] = eb + p0; cur[2 * t + 1] = eb + p0;
    }
    __syncthreads();
    // packed CSR words (coalesced)
    const int seg0 = b * SEGB;
    const int nseg = min(SEGB, M_SEG - seg0);
    if (t < nseg) {
        const int pc = hist[t] + (hist[t] & 1);
        ofs[seg0 + t] = (unsigned)(base + lofs[t]) | ((unsigned)pc << 24);
    }
    // scatter within bucket (cur = running cursors)
    for (int j = s + t; j < e; j += 512) {
        const int2 p = epA[j];
        const int sl = ((unsigned)p.x) >> 16;
        const int col = p.x & 0xFFFF;
        const int seg = seg0 + sl;
        const int g = seg / N_NODES;
        const int pos = atomicAdd(&cur[sl], 1);
        epB[base + pos] = make_int2((col << 9) | (g << 7), p.y);
    }
    // pad entries (slots disjoint from scatter writes -> no sync needed)
    if (t < nseg && (hist[t] & 1))
        epB[base + lofs[t] + hist[t]] = make_int2(0, 0);
}

// ---------------------------------------------------------------------------
// Octo-segment CSR SpMM: one wave = 8 segments (8 lanes x 8 features each;
// N_NODES % 8 == 0 so an octant never straddles a group). Pair-wise int4 ep
// loads (2 edges / load, segments even-padded), uint4 16B gathers. Branch-
// free: clamped always-valid ep loads; BOTH the gather address and the
// weight are predicated (address -> 0 for exhausted/empty lanes, so a
// garbage ep word from an uninitialized gap can never form a wild gather).
// ---------------------------------------------------------------------------
__global__ __launch_bounds__(256) void spmm_csr_kernel(
    const unsigned short* __restrict__ xb, const int2* __restrict__ ep,
    const unsigned* __restrict__ ofs, unsigned short* __restrict__ tmpb)
{
    const int w   = (blockIdx.x * 256 + threadIdx.x) >> 6;   // wave id
    const int tl  = threadIdx.x & 63;
    const int o   = tl >> 3;            // octant 0..7
    const int ls  = tl & 7;             // lane-in-octant
    const int seg = w * 8 + o;
    const int g   = seg / N_NODES;
    const int row = seg - g * N_NODES;

    const char* __restrict__ xbb = (const char*)xb + ls * 16;

    const unsigned po = ofs[seg];
    int j       = (int)(po & 0xFFFFFFu);
    const int e = j + (int)(po >> 24);           // even count (padded)
    const int emax2 = (e - 2 < j) ? j : (e - 2); // even, always-valid pair base

    float a0 = 0.f, a1 = 0.f, a2 = 0.f, a3 = 0.f;
    float a4 = 0.f, a5 = 0.f, a6 = 0.f, a7 = 0.f;

#define ACC8(v, r)                                          \
    a0 = fmaf(v, __uint_as_float((r).x << 16), a0);         \
    a1 = fmaf(v, __uint_as_float((r).x & 0xFFFF0000u), a1); \
    a2 = fmaf(v, __uint_as_float((r).y << 16), a2);         \
    a3 = fmaf(v, __uint_as_float((r).y & 0xFFFF0000u), a3); \
    a4 = fmaf(v, __uint_as_float((r).z << 16), a4);         \
    a5 = fmaf(v, __uint_as_float((r).z & 0xFFFF0000u), a5); \
    a6 = fmaf(v, __uint_as_float((r).w << 16), a6);         \
    a7 = fmaf(v, __uint_as_float((r).w & 0xFFFF0000u), a7);

    while (__ballot(j < e)) {
        const int jc0 = min(j, emax2);
        const int jc1 = min(j + 2, emax2);
        const int4 q0 = *(const int4*)&ep[jc0];   // edges jc0, jc0+1
        const int4 q1 = *(const int4*)&ep[jc1];   // edges jc1, jc1+1
        const bool cA = j < e;            // covers j and j+1 (e-j even)
        const bool cB = (j + 2) < e;      // covers j+2 and j+3
        // predicated gather addresses: garbage ep data can never fault
        const int o0 = cA ? q0.x : 0;
        const int o1 = cA ? q0.z : 0;
        const int o2 = cB ? q1.x : 0;
        const int o3 = cB ? q1.z : 0;
        const uint4 r0 = *(const uint4*)(xbb + o0);
        const uint4 r1 = *(const uint4*)(xbb + o1);
        const uint4 r2 = *(const uint4*)(xbb + o2);
        const uint4 r3 = *(const uint4*)(xbb + o3);
        const float v0 = cA ? __int_as_float(q0.y) : 0.f;
        const float v1 = cA ? __int_as_float(q0.w) : 0.f;
        const float v2 = cB ? __int_as_float(q1.y) : 0.f;
        const float v3 = cB ? __int_as_float(q1.w) : 0.f;
        ACC8(v0, r0)
        ACC8(v1, r1)
        ACC8(v2, r2)
        ACC8(v3, r3)
        j += 4;
    }
#undef ACC8

    const unsigned o0w = (unsigned)f2bf(a0) | ((unsigned)f2bf(a1) << 16);
    const unsigned o1w = (unsigned)f2bf(a2) | ((unsigned)f2bf(a3) << 16);
    const unsigned o2w = (unsigned)f2bf(a4) | ((unsigned)f2bf(a5) << 16);
    const unsigned o3w = (unsigned)f2bf(a6) | ((unsigned)f2bf(a7) << 16);
    *(uint4*)((char*)tmpb + (size_t)row * 512 + g * 128 + ls * 16) =
        make_uint4(o0w, o1w, o2w, o3w);
}

// ---------------------------------------------------------------------------
// MFMA GEMM: C[M,256] = tmp_bf @ W + bias.  A: [M_PAD,256] bf16 row-major,
// Bt: [256,256] bf16 n-major/k-contiguous. 128x128 tile, BK=32, 4 waves.
// ---------------------------------------------------------------------------
#define TBK 32
#define LDP 40   // padded LDS row (ushorts): 80B stride spreads all 32 banks

__global__ __launch_bounds__(256) void gemm_mfma_kernel(
    const unsigned short* __restrict__ A, const unsigned short* __restrict__ Bt,
    const float* __restrict__ bias, float* __restrict__ C)
{
    __shared__ unsigned short As[128][LDP];   // 10 KB
    __shared__ unsigned short Bs[128][LDP];   // 10 KB

    const int tid = threadIdx.x;
    const int wid = tid >> 6, lane = tid & 63;
    const int wm = (wid & 1) * 64, wn = (wid >> 1) * 64;
    const int lm = lane & 15, lq = lane >> 4;
    const int row0 = blockIdx.x * 128, col0 = blockIdx.y * 128;

    f32x4 acc[4][4] = {};

    for (int k0 = 0; k0 < D_FEAT; k0 += TBK) {
        // A tile: 128 rows x 32 k; 64B/row = 4 x 16B chunks; 2 chunks/thread
        #pragma unroll
        for (int l = 0; l < 2; ++l) {
            const int chunk = tid + l * 256;     // 0..511
            const int r = chunk >> 2;
            const int c = (chunk & 3) * 8;
            uint4 v = make_uint4(0u, 0u, 0u, 0u);
            const int gr = row0 + r;
            if (gr < N_NODES)
                v = *(const uint4*)&A[(long long)gr * D_FEAT + k0 + c];
            *(uint4*)&As[r][c] = v;
        }
        #pragma unroll
        for (int l = 0; l < 2; ++l) {
            const int chunk = tid + l * 256;
            const int r = chunk >> 2;
            const int c = (chunk & 3) * 8;
            *(uint4*)&Bs[r][c] =
                *(const uint4*)&Bt[(long long)(col0 + r) * D_FEAT + k0 + c];
        }
        __syncthreads();

        bf16x8 af[4], bfr[4];
        #pragma unroll
        for (int mi = 0; mi < 4; ++mi)
            af[mi] = *(const bf16x8*)&As[wm + mi * 16 + lm][lq * 8];
        #pragma unroll
        for (int ni = 0; ni < 4; ++ni)
            bfr[ni] = *(const bf16x8*)&Bs[wn + ni * 16 + lm][lq * 8];
        #pragma unroll
        for (int mi = 0; mi < 4; ++mi)
            #pragma unroll
            for (int ni = 0; ni < 4; ++ni)
                acc[mi][ni] = __builtin_amdgcn_mfma_f32_16x16x32_bf16(
                    af[mi], bfr[ni], acc[mi][ni], 0, 0, 0);
        __syncthreads();
    }

    // D layout: col = lane&15, row = (lane>>4)*4 + reg
    #pragma unroll
    for (int mi = 0; mi < 4; ++mi) {
        #pragma unroll
        for (int ni = 0; ni < 4; ++ni) {
            const int n = col0 + wn + ni * 16 + lm;
            const float b = bias[n];
            #pragma unroll
            for (int r = 0; r < 4; ++r) {
                const int m = row0 + wm + mi * 16 + lq * 4 + r;
                if (m < N_NODES)
                    C[(long long)m * D_FEAT + n] = acc[mi][ni][r] + b;
            }
        }
    }
}

// ---------------------------------------------------------------------------
// Fallback path (atomic f32 spmm + f32 GEMM) — only if ws too small.
// ---------------------------------------------------------------------------
__global__ __launch_bounds__(256) void spmm_scatter_kernel(
    const float* __restrict__ x, const int* __restrict__ edge_row,
    const int* __restrict__ edge_col, const float* __restrict__ edge_val,
    float* __restrict__ tmp)
{
    const long long gtid = (long long)blockIdx.x * blockDim.x + threadIdx.x;
    const int wave = (int)(gtid >> 6);
    const int lane = threadIdx.x & 63;
    if (wave >= TOT_E) return;
    const int g = wave / E_EDGES;
    const int row = edge_row[wave];
    const int col = edge_col[wave];
    const float val = edge_val[wave];
    atomicAdd(&tmp[(long long)row * D_FEAT + g * DG + lane],
              val * x[(long long)col * D_FEAT + g * DG + lane]);
}

__global__ __launch_bounds__(256) void gemm_bias_kernel(
    const float* __restrict__ A, const float* __restrict__ W,
    const float* __restrict__ bias, float* __restrict__ C)
{
    __shared__ float Asf[64][68];
    __shared__ float Wsf[64][68];
    const int tid = threadIdx.x;
    const int tx = tid & 15, ty = tid >> 4;
    const int row0 = blockIdx.x * 64, col0 = blockIdx.y * 64;
    float acc[4][4] = {};
    for (int k0 = 0; k0 < D_FEAT; k0 += 64) {
        #pragma unroll
        for (int l = 0; l < 4; ++l) {
            const int linear = tid + l * 256;
            const int ar = linear >> 4, ac = (linear & 15) << 2;
            float4 v = make_float4(0.f, 0.f, 0.f, 0.f);
            const int gr = row0 + ar;
            if (gr < N_NODES) v = *(const float4*)&A[(long long)gr * D_FEAT + k0 + ac];
            Asf[ac + 0][ar] = v.x; Asf[ac + 1][ar] = v.y;
            Asf[ac + 2][ar] = v.z; Asf[ac + 3][ar] = v.w;
        }
        #pragma unroll
        for (int l = 0; l < 4; ++l) {
            const int linear = tid + l * 256;
            const int wr = linear >> 4, wc = (linear & 15) << 2;
            *(float4*)&Wsf[wr][wc] =
                *(const float4*)&W[(long long)(k0 + wr) * D_FEAT + col0 + wc];
        }
        __syncthreads();
        #pragma unroll
        for (int k = 0; k < 64; ++k) {
            const float4 a4 = *(const float4*)&Asf[k][ty * 4];
            const float4 b4 = *(const float4*)&Wsf[k][tx * 4];
            const float a[4] = {a4.x, a4.y, a4.z, a4.w};
            const float b[4] = {b4.x, b4.y, b4.z, b4.w};
            #pragma unroll
            for (int i = 0; i < 4; ++i)
                #pragma unroll
                for (int j = 0; j < 4; ++j) acc[i][j] += a[i] * b[j];
        }
        __syncthreads();
    }
    const float4 b4 = *(const float4*)&bias[col0 + tx * 4];
    #pragma unroll
    for (int i = 0; i < 4; ++i) {
        const int gr = row0 + ty * 4 + i;
        if (gr >= N_NODES) continue;
        float4 v;
        v.x = acc[i][0] + b4.x; v.y = acc[i][1] + b4.y;
        v.z = acc[i][2] + b4.z; v.w = acc[i][3] + b4.w;
        *(float4*)&C[(long long)gr * D_FEAT + col0 + tx * 4] = v;
    }
}

// ---------------------------------------------------------------------------
extern "C" void kernel_launch(void* const* d_in, const int* in_sizes, int n_in,
                              void* d_out, int out_size, void* d_ws, size_t ws_size,
                              hipStream_t stream)
{
    const float* x        = (const float*)d_in[0];
    const int*   edge_row = (const int*)d_in[1];
    const int*   edge_col = (const int*)d_in[2];
    const float* edge_val = (const float*)d_in[3];
    const float* weight   = (const float*)d_in[4];
    const float* bias     = (const float*)d_in[5];
    float* out = (float*)d_out;

    char* p = (char*)d_ws;
    auto alloc = [&](size_t bytes) {
        char* r = p;
        p += (bytes + 255) & ~(size_t)255;
        return r;
    };
    unsigned short* xb   = (unsigned short*)alloc((size_t)N_NODES * D_FEAT * 2); // 25.6 MB
    unsigned short* tmpb = (unsigned short*)alloc((size_t)M_PAD * D_FEAT * 2);   // 25.6 MB
    unsigned short* Wt   = (unsigned short*)alloc((size_t)D_FEAT * D_FEAT * 2);  // 128 KB
    int2* epB = (int2*)alloc(((size_t)TOT_E + (size_t)NB1 * PADMAX + 8)
                             * sizeof(int2));                                    // 27.2 MB
    int* cntA = (int*)alloc((size_t)NB1 * sizeof(int));
    int* ofsA = (int*)alloc((size_t)(NB1 + 1) * sizeof(int));
    int* curA = (int*)alloc((size_t)NB1 * sizeof(int));
    unsigned* ofs = (unsigned*)alloc((size_t)M_SEG * sizeof(unsigned));          // 800 KB
    const size_t needed = (size_t)(p - (char*)d_ws);

    // epA aliases tmpb: TOT_E*8 = 25,600,000 B <= M_PAD*256*2 = 25,624,576 B.
    // epA is dead before spmm_csr writes tmpb (stream-ordered).
    int2* epA = (int2*)tmpb;

    if (ws_size >= needed) {
        hipMemsetAsync(cntA, 0, (size_t)NB1 * sizeof(int), stream);
        convert_x_kernel<<<(N_NODES * D_FEAT / 8 + 255) / 256, 256, 0, stream>>>(x, xb);
        convert_w_kernel<<<D_FEAT, D_FEAT, 0, stream>>>(weight, Wt);
        countA_kernel<<<CA_BLOCKS, 1024, 0, stream>>>(edge_row, cntA);
        scanA_kernel<<<1, 256, 0, stream>>>(cntA, ofsA, curA);
        scatterA_kernel<<<CA_BLOCKS, 1024, 0, stream>>>(
            edge_row, edge_col, edge_val, curA, epA);
        sortB_kernel<<<NB1, 512, 0, stream>>>(epA, ofsA, epB, ofs);
        spmm_csr_kernel<<<(M_SEG / 8) * 64 / 256, 256, 0, stream>>>(xb, epB, ofs, tmpb);
        dim3 grid(M_PAD / 128, D_FEAT / 128);
        gemm_mfma_kernel<<<grid, 256, 0, stream>>>(tmpb, Wt, bias, out);
    } else {
        float* tmp = (float*)d_ws;
        hipMemsetAsync(tmp, 0, (size_t)N_NODES * D_FEAT * sizeof(float), stream);
        const long long total_threads = (long long)TOT_E * 64;
        spmm_scatter_kernel<<<(int)((total_threads + 255) / 256), 256, 0, stream>>>(
            x, edge_row, edge_col, edge_val, tmp);
        dim3 grid2((N_NODES + 63) / 64, D_FEAT / 64);
        gemm_bias_kernel<<<grid2, 256, 0, stream>>>(tmp, weight, bias, out);
    }
}